// Round 10
// baseline (354.250 us; speedup 1.0000x reference)
//
#include <hip/hip_runtime.h>

typedef __attribute__((ext_vector_type(4))) float f4;
typedef __attribute__((ext_vector_type(8))) short s8;
typedef __attribute__((ext_vector_type(4))) short s4;

__device__ __forceinline__ short f2bf(float f){
  unsigned u = __builtin_bit_cast(unsigned, f);
  u = (u + 0x7fffu + ((u >> 16) & 1u)) >> 16;
  return (short)u;
}
__device__ __forceinline__ float bf2f(short h){
  unsigned u = ((unsigned)(unsigned short)h) << 16;
  return __builtin_bit_cast(float, u);
}
__device__ __forceinline__ f4 mfma16(s8 a, s8 b, f4 c){
  return __builtin_amdgcn_mfma_f32_16x16x32_bf16(a, b, c, 0, 0, 0);
}
__device__ __forceinline__ s8 cfrag(const float* p){
  f4 a = *(const f4*)p; f4 b = *(const f4*)(p + 4);
  s8 t = {f2bf(a[0]), f2bf(a[1]), f2bf(a[2]), f2bf(a[3]),
          f2bf(b[0]), f2bf(b[1]), f2bf(b[2]), f2bf(b[3])};
  return t;
}
__device__ __forceinline__ s8 nfrag(const float* p){
  f4 a = *(const f4*)p; f4 b = *(const f4*)(p + 4);
  float ss = a[0]*a[0]+a[1]*a[1]+a[2]*a[2]+a[3]*a[3]
           + b[0]*b[0]+b[1]*b[1]+b[2]*b[2]+b[3]*b[3];
  ss += __shfl_xor(ss, 16); ss += __shfl_xor(ss, 32);
  float f = 1.0f / fmaxf(sqrtf(ss), 1e-12f);
  s8 t = {f2bf(a[0]*f), f2bf(a[1]*f), f2bf(a[2]*f), f2bf(a[3]*f),
          f2bf(b[0]*f), f2bf(b[1]*f), f2bf(b[2]*f), f2bf(b[3]*f)};
  return t;
}
// tanh-form GELU via hardware exp; overflow-safe (e=inf -> t=1)
__device__ __forceinline__ float gelu(float x){
  float x3 = x * x * x;
  float e = __expf(1.5957691216f * (x + 0.044715f * x3));
  float t = 1.0f - 2.0f / (e + 1.0f);
  return 0.5f * x * (1.0f + t);
}
#define SWZ(row) ((((row) ^ ((row) >> 3)) & 7) << 3)

// ---------------------------------------------------------------- k_prep
__global__ __launch_bounds__(256) void k_prep(
    const float* __restrict__ vw, const float* __restrict__ ow,
    const float* __restrict__ iw, const float* __restrict__ fw,
    const float* __restrict__ dw, const float* __restrict__ tbl,
    const float* __restrict__ c0b, const float* __restrict__ c0w,
    const float* __restrict__ c2w, const int* __restrict__ rpi,
    short* __restrict__ wsw, float* __restrict__ bias)
{
  if (blockIdx.x < 288) {
    int e0 = (blockIdx.x * 256 + threadIdx.x) * 4;
#pragma unroll
    for (int i = 0; i < 4; ++i) {
      int e = e0 + i;
      float v;
      if (e < 16384) v = vw[e];
      else if (e < 32768) v = ow[e - 16384];
      else if (e < 98304) v = iw[e - 32768];
      else if (e < 163840) v = fw[e - 98304];
      else v = dw[e - 163840];
      wsw[e] = f2bf(v);
    }
    return;
  }
  __shared__ float tb[900];
  __shared__ int orAcc;
  int tid = threadIdx.x;
  if (tid == 0) orAcc = 0;
  __syncthreads();
  int my = 0;
  for (int i = tid; i < 2048; i += 256) my |= rpi[2 * i + 1];
  atomicOr(&orAcc, my);
  if (tid < 225) {
    float t0 = tbl[tid * 2 + 0], t1 = tbl[tid * 2 + 1];
    float s0 = 0.f, s1 = 0.f, s2 = 0.f, s3 = 0.f;
    for (int j = 0; j < 512; ++j) {
      float hv = fmaxf(t0 * c0w[j * 2] + t1 * c0w[j * 2 + 1] + c0b[j], 0.f);
      s0 += hv * c2w[j];
      s1 += hv * c2w[512 + j];
      s2 += hv * c2w[1024 + j];
      s3 += hv * c2w[1536 + j];
    }
    tb[tid * 4 + 0] = s0; tb[tid * 4 + 1] = s1;
    tb[tid * 4 + 2] = s2; tb[tid * 4 + 3] = s3;
  }
  __syncthreads();
  bool i64 = (orAcc == 0);
#pragma unroll
  for (int it = 0; it < 64; ++it) {
    int e = it * 256 + tid;
    int rem = e & 4095;
    int h = e >> 12;
    int idx = i64 ? rpi[2 * rem] : rpi[rem];
    float v = tb[idx * 4 + h];
    bias[e] = 16.f / (1.f + __expf(-v));
  }
}

// ---------------------------------------------------------------- k_attn
// (proven form: hsw staged once, Vt/P reuse region, 48 KB, 3 blk/CU)
__global__ __launch_bounds__(256, 3) void k_attn(
    const float* __restrict__ hswp, const float* __restrict__ qg,
    const float* __restrict__ kg, const float* __restrict__ lsc,
    const float* __restrict__ vb, const short* __restrict__ wvb,
    const float* __restrict__ bias, short* __restrict__ ctx)
{
  __shared__ short lds[24576];
  const int bw = blockIdx.x, tid = threadIdx.x;
  const int lane = tid & 63, h = tid >> 6;
  const int r16 = lane & 15, b4 = lane >> 4;

  const float* qp = qg + ((size_t)bw * 4 + h) * 2048;
  const float* kp = kg + ((size_t)bw * 4 + h) * 2048;
  const float* hp = hswp + (size_t)bw * 8192;

  s8 qf[4], kf[4];
#pragma unroll
  for (int t = 0; t < 4; ++t) qf[t] = nfrag(qp + (t * 16 + r16) * 32 + b4 * 8);
#pragma unroll
  for (int t = 0; t < 4; ++t) kf[t] = nfrag(kp + (t * 16 + r16) * 32 + b4 * 8);

  {
    int row = tid >> 2, c0 = (tid & 3) * 32;
    const float* src = hp + row * 128 + c0;
    short* dst = &lds[row * 136 + c0];
#pragma unroll
    for (int j = 0; j < 4; ++j)
      *(s8*)(dst + j * 8) = cfrag(src + j * 8);
  }
  __syncthreads();

  f4 vac[2][4];
#pragma unroll
  for (int ct = 0; ct < 2; ++ct)
#pragma unroll
    for (int tt = 0; tt < 4; ++tt) vac[ct][tt] = (f4){0.f, 0.f, 0.f, 0.f};
#pragma unroll
  for (int ks = 0; ks < 4; ++ks) {
    s8 bfr[4];
#pragma unroll
    for (int tt = 0; tt < 4; ++tt)
      bfr[tt] = *(const s8*)&lds[(tt * 16 + r16) * 136 + ks * 32 + b4 * 8];
#pragma unroll
    for (int ct = 0; ct < 2; ++ct) {
      s8 af = *(const s8*)(wvb + (size_t)(h * 32 + ct * 16 + r16) * 128 + ks * 32 + b4 * 8);
#pragma unroll
      for (int tt = 0; tt < 4; ++tt)
        vac[ct][tt] = mfma16(af, bfr[tt], vac[ct][tt]);
    }
  }

  f4 sac[4][4];
#pragma unroll
  for (int a = 0; a < 4; ++a)
#pragma unroll
    for (int b = 0; b < 4; ++b) sac[a][b] = (f4){0.f, 0.f, 0.f, 0.f};
#pragma unroll
  for (int kt = 0; kt < 4; ++kt)
#pragma unroll
    for (int qt = 0; qt < 4; ++qt)
      sac[kt][qt] = mfma16(kf[kt], qf[qt], sac[kt][qt]);

  float scal = __expf(fminf(lsc[h], 4.60517019f));
  float rden[4];
#pragma unroll
  for (int qt = 0; qt < 4; ++qt) {
    float m = -1e30f;
#pragma unroll
    for (int kt = 0; kt < 4; ++kt) {
      f4 bv = *(const f4*)(bias + (h * 64 + qt * 16 + r16) * 64 + kt * 16 + b4 * 4);
#pragma unroll
      for (int r = 0; r < 4; ++r) {
        float sv = sac[kt][qt][r] * scal + bv[r];
        sac[kt][qt][r] = sv;
        m = fmaxf(m, sv);
      }
    }
    m = fmaxf(m, __shfl_xor(m, 16));
    m = fmaxf(m, __shfl_xor(m, 32));
    float sum = 0.f;
#pragma unroll
    for (int kt = 0; kt < 4; ++kt)
#pragma unroll
      for (int r = 0; r < 4; ++r) {
        float e = __expf(sac[kt][qt][r] - m);
        sac[kt][qt][r] = e;
        sum += e;
      }
    sum += __shfl_xor(sum, 16);
    sum += __shfl_xor(sum, 32);
    rden[qt] = 1.0f / sum;
  }

  __syncthreads();

  short* Vt = &lds[h * 6144];
  short* P  = &lds[h * 6144 + 2048];

#pragma unroll
  for (int ct = 0; ct < 2; ++ct)
#pragma unroll
    for (int r = 0; r < 4; ++r) {
      int row = ct * 16 + b4 * 4 + r;
      float bvl = vb[h * 32 + row];
#pragma unroll
      for (int tt = 0; tt < 4; ++tt) {
        int col = tt * 16 + r16;
        Vt[row * 64 + (col ^ SWZ(row))] = f2bf(vac[ct][tt][r] + bvl);
      }
    }
#pragma unroll
  for (int qt = 0; qt < 4; ++qt) {
    int q = qt * 16 + r16;
#pragma unroll
    for (int kt = 0; kt < 4; ++kt) {
      s4 p4;
#pragma unroll
      for (int r = 0; r < 4; ++r) p4[r] = f2bf(sac[kt][qt][r] * rden[qt]);
      *(s4*)&P[q * 64 + ((kt * 16 + b4 * 4) ^ SWZ(q))] = p4;
    }
  }

  f4 cac[2][4];
#pragma unroll
  for (int a = 0; a < 2; ++a)
#pragma unroll
    for (int b = 0; b < 4; ++b) cac[a][b] = (f4){0.f, 0.f, 0.f, 0.f};
#pragma unroll
  for (int ks = 0; ks < 2; ++ks) {
    s8 pf[4];
#pragma unroll
    for (int qt = 0; qt < 4; ++qt) {
      int q = qt * 16 + r16;
      pf[qt] = *(const s8*)&P[q * 64 + ((ks * 32 + b4 * 8) ^ SWZ(q))];
    }
#pragma unroll
    for (int dt = 0; dt < 2; ++dt) {
      int row = dt * 16 + r16;
      s8 vf = *(const s8*)&Vt[row * 64 + ((ks * 32 + b4 * 8) ^ SWZ(row))];
#pragma unroll
      for (int qt = 0; qt < 4; ++qt)
        cac[dt][qt] = mfma16(vf, pf[qt], cac[dt][qt]);
    }
  }
#pragma unroll
  for (int qt = 0; qt < 4; ++qt)
#pragma unroll
    for (int dt = 0; dt < 2; ++dt) {
      s4 o;
#pragma unroll
      for (int r = 0; r < 4; ++r) o[r] = f2bf(cac[dt][qt][r]);
      *(s4*)(ctx + (size_t)(bw * 64 + qt * 16 + r16) * 128 + h * 32 + dt * 16 + b4 * 4) = o;
    }
}

// ---------------------------------------------------------------- k_fuse
// EXACT R6 structure (proven 138 us): block-shared Bs panel, separate
// wave-private hst/f1t tiles, direct staging, residual from LDS,
// launch_bounds(256,2). Single isolated change: tanh GELU (fewer VALU).
__global__ __launch_bounds__(256, 2) void k_fuse(
    const short* __restrict__ ctx, const short* __restrict__ owb,
    const float* __restrict__ ob, const float* __restrict__ emb,
    const float* __restrict__ lnbw, const float* __restrict__ lnbb,
    const short* __restrict__ iwb, const float* __restrict__ ib,
    const short* __restrict__ fwb, const float* __restrict__ fb,
    const float* __restrict__ lnaw, const float* __restrict__ lnab,
    short* __restrict__ lo)
{
  __shared__ short Bs[128 * 136];      // 34816 B, shared weight panel
  __shared__ short hst[4][2184];       // 17472 B
  __shared__ short f1t[4][2184];       // 17472 B
  const int tid = threadIdx.x, lane = tid & 63, wv = tid >> 6;
  const int r16 = lane & 15, b4 = lane >> 4;
  const int obase = blockIdx.x * 64 + wv * 16;

  // ---- stage out_dense weights
#pragma unroll
  for (int it = 0; it < 8; ++it) {
    int ch = it * 256 + tid, n = ch >> 4, k8 = ch & 15;
    *(s8*)&Bs[n * 136 + k8 * 8] = *(const s8*)(owb + (size_t)n * 128 + k8 * 8);
  }
  __syncthreads();

  // ---- out-GEMM with inverse window-reverse gather
  int m = obase + r16;
  int bb = m >> 12, rimg = (m >> 6) & 63, cimg = m & 63;
  long tok = ((long)(bb * 64 + (rimg >> 3) * 8 + (cimg >> 3)) << 6)
           + (rimg & 7) * 8 + (cimg & 7);
  const short* ap = ctx + tok * 128;

  f4 acc[8];
#pragma unroll
  for (int nt = 0; nt < 8; ++nt) acc[nt] = (f4){0.f, 0.f, 0.f, 0.f};
#pragma unroll
  for (int ks = 0; ks < 4; ++ks) {
    s8 af = *(const s8*)(ap + ks * 32 + b4 * 8);
#pragma unroll
    for (int nt = 0; nt < 8; ++nt) {
      s8 bf = *(const s8*)&Bs[(nt * 16 + r16) * 136 + ks * 32 + b4 * 8];
      acc[nt] = mfma16(af, bf, acc[nt]);
    }
  }
  // LN_before + emb -> hst
#pragma unroll
  for (int r = 0; r < 4; ++r) {
    int t = b4 * 4 + r;
    long orow = obase + t;
    float x[8];
    float s = 0.f, s2 = 0.f;
#pragma unroll
    for (int nt = 0; nt < 8; ++nt) {
      int c = nt * 16 + r16;
      x[nt] = acc[nt][r] + ob[c];
      s += x[nt]; s2 += x[nt] * x[nt];
    }
    s += __shfl_xor(s, 1); s += __shfl_xor(s, 2); s += __shfl_xor(s, 4); s += __shfl_xor(s, 8);
    s2 += __shfl_xor(s2, 1); s2 += __shfl_xor(s2, 2); s2 += __shfl_xor(s2, 4); s2 += __shfl_xor(s2, 8);
    float mu = s * (1.f / 128.f);
    float var = s2 * (1.f / 128.f) - mu * mu;
    float rs = rsqrtf(var + 1e-5f);
#pragma unroll
    for (int nt = 0; nt < 8; ++nt) {
      int c = nt * 16 + r16;
      float y = (x[nt] - mu) * rs * lnbw[c] + lnbb[c] + emb[orow * 128 + c];
      hst[wv][t * 136 + c] = f2bf(y);
    }
  }

  // hs A-fragments (wave-private)
  s8 af1[4];
#pragma unroll
  for (int ks = 0; ks < 4; ++ks)
    af1[ks] = *(const s8*)&hst[wv][r16 * 136 + ks * 32 + b4 * 8];

  f4 acc2[8];
#pragma unroll
  for (int nt = 0; nt < 8; ++nt) acc2[nt] = (f4){0.f, 0.f, 0.f, 0.f};

  for (int cc = 0; cc < 4; ++cc) {
    int n0 = cc * 128;
    __syncthreads();
#pragma unroll
    for (int it = 0; it < 8; ++it) {
      int ch = it * 256 + tid, n = ch >> 4, k8 = ch & 15;
      *(s8*)&Bs[n * 136 + k8 * 8] = *(const s8*)(iwb + (size_t)(n0 + n) * 128 + k8 * 8);
    }
    __syncthreads();
    // ffn1 chunk
    f4 a1[8];
#pragma unroll
    for (int nt = 0; nt < 8; ++nt) a1[nt] = (f4){0.f, 0.f, 0.f, 0.f};
#pragma unroll
    for (int ks = 0; ks < 4; ++ks) {
#pragma unroll
      for (int nt = 0; nt < 8; ++nt) {
        s8 bf = *(const s8*)&Bs[(nt * 16 + r16) * 136 + ks * 32 + b4 * 8];
        a1[nt] = mfma16(af1[ks], bf, a1[nt]);
      }
    }
    // GELU -> f1t (wave-private)
#pragma unroll
    for (int r = 0; r < 4; ++r) {
      int t = b4 * 4 + r;
#pragma unroll
      for (int nt = 0; nt < 8; ++nt) {
        int c = nt * 16 + r16;
        float g = gelu(a1[nt][r] + ib[n0 + c]);
        f1t[wv][t * 136 + c] = f2bf(g);
      }
    }
    __syncthreads();
#pragma unroll
    for (int it = 0; it < 8; ++it) {
      int ch = it * 256 + tid, n = ch >> 4, k8 = ch & 15;
      *(s8*)&Bs[n * 136 + k8 * 8] = *(const s8*)(fwb + (size_t)n * 512 + n0 + k8 * 8);
    }
    __syncthreads();
    // ffn2 partial K
#pragma unroll
    for (int ks = 0; ks < 4; ++ks) {
      s8 af2 = *(const s8*)&f1t[wv][r16 * 136 + ks * 32 + b4 * 8];
#pragma unroll
      for (int nt = 0; nt < 8; ++nt) {
        s8 bf = *(const s8*)&Bs[(nt * 16 + r16) * 136 + ks * 32 + b4 * 8];
        acc2[nt] = mfma16(af2, bf, acc2[nt]);
      }
    }
  }

  // ---- LN_after + residual (from hst) -> lo
#pragma unroll
  for (int r = 0; r < 4; ++r) {
    int t = b4 * 4 + r;
    long orow = obase + t;
    float x[8];
    float s = 0.f, s2 = 0.f;
#pragma unroll
    for (int nt = 0; nt < 8; ++nt) {
      int c = nt * 16 + r16;
      x[nt] = acc2[nt][r] + fb[c];
      s += x[nt]; s2 += x[nt] * x[nt];
    }
    s += __shfl_xor(s, 1); s += __shfl_xor(s, 2); s += __shfl_xor(s, 4); s += __shfl_xor(s, 8);
    s2 += __shfl_xor(s2, 1); s2 += __shfl_xor(s2, 2); s2 += __shfl_xor(s2, 4); s2 += __shfl_xor(s2, 8);
    float mu = s * (1.f / 128.f);
    float var = s2 * (1.f / 128.f) - mu * mu;
    float rs = rsqrtf(var + 1e-5f);
#pragma unroll
    for (int nt = 0; nt < 8; ++nt) {
      int c = nt * 16 + r16;
      float y = (x[nt] - mu) * rs * lnaw[c] + lnab[c] + bf2f(hst[wv][t * 136 + c]);
      lo[orow * 128 + c] = f2bf(y);
    }
  }
}

// ---------------------------------------------------------------- k_merge
__global__ __launch_bounds__(256) void k_merge(
    const short* __restrict__ lo, const short* __restrict__ dwb,
    const float* __restrict__ dsw, const float* __restrict__ dsb,
    float* __restrict__ out)
{
  __shared__ short Bs[256 * 136];
  const int tid = threadIdx.x;
  const int lane = tid & 63, wv = tid >> 6, r16 = lane & 15, b4 = lane >> 4;
  const int mrow = blockIdx.x * 64 + wv * 16;
  f4 acc[16];
#pragma unroll
  for (int nt = 0; nt < 16; ++nt) acc[nt] = (f4){0.f, 0.f, 0.f, 0.f};
  for (int kc = 0; kc < 4; ++kc) {
    if (kc) __syncthreads();
#pragma unroll
    for (int it = 0; it < 16; ++it) {
      int ch = it * 256 + tid, n = ch >> 4, k8 = ch & 15;
      *(s8*)&Bs[n * 136 + k8 * 8] = *(const s8*)(dwb + (size_t)n * 512 + kc * 128 + k8 * 8);
    }
    __syncthreads();
    int m = mrow + r16;
    int bb = m >> 10, p = m & 1023, ii = p >> 5, jj = p & 31;
    long row = (long)bb * 4096 + (2 * ii + (kc & 1)) * 64 + (2 * jj + (kc >> 1));
    const short* ap = lo + row * 128;
#pragma unroll
    for (int ks = 0; ks < 4; ++ks) {
      s8 af = *(const s8*)(ap + ks * 32 + b4 * 8);
#pragma unroll
      for (int nt = 0; nt < 16; ++nt) {
        s8 bf = *(const s8*)&Bs[(nt * 16 + r16) * 136 + ks * 32 + b4 * 8];
        acc[nt] = mfma16(af, bf, acc[nt]);
      }
    }
  }
#pragma unroll
  for (int r = 0; r < 4; ++r) {
    size_t m = mrow + b4 * 4 + r;
    float x[16];
    float s = 0.f, s2 = 0.f;
#pragma unroll
    for (int nt = 0; nt < 16; ++nt) {
      x[nt] = acc[nt][r];
      s += x[nt]; s2 += x[nt] * x[nt];
    }
    s += __shfl_xor(s, 1); s += __shfl_xor(s, 2); s += __shfl_xor(s, 4); s += __shfl_xor(s, 8);
    s2 += __shfl_xor(s2, 1); s2 += __shfl_xor(s2, 2); s2 += __shfl_xor(s2, 4); s2 += __shfl_xor(s2, 8);
    float mu = s * (1.f / 256.f);
    float var = s2 * (1.f / 256.f) - mu * mu;
    float rs = rsqrtf(var + 1e-5f);
#pragma unroll
    for (int nt = 0; nt < 16; ++nt) {
      int c = nt * 16 + r16;
      out[m * 256 + c] = (x[nt] - mu) * rs * dsw[c] + dsb[c];
    }
  }
}

// ---------------------------------------------------------------- launch
extern "C" void kernel_launch(void* const* d_in, const int* in_sizes, int n_in,
                              void* d_out, int out_size, void* d_ws, size_t ws_size,
                              hipStream_t stream)
{
  const float* out_dense_b = (const float*)d_in[0];
  const float* out_dense_w = (const float*)d_in[1];
  const float* rel_tbl     = (const float*)d_in[2];
  const float* cpb0_b      = (const float*)d_in[3];
  const float* cpb0_w      = (const float*)d_in[4];
  const float* cpb2_w      = (const float*)d_in[5];
  const float* value_b     = (const float*)d_in[6];
  const float* value_w     = (const float*)d_in[7];
  const float* logit_scale = (const float*)d_in[8];
  const float* inter_b     = (const float*)d_in[9];
  const float* inter_w     = (const float*)d_in[10];
  const float* ln_after_b  = (const float*)d_in[11];
  const float* ln_after_w  = (const float*)d_in[12];
  const float* ln_before_b = (const float*)d_in[13];
  const float* ln_before_w = (const float*)d_in[14];
  const float* ffn_out_b   = (const float*)d_in[15];
  const float* ffn_out_w   = (const float*)d_in[16];
  const float* ds_norm_b   = (const float*)d_in[17];
  const float* ds_norm_w   = (const float*)d_in[18];
  const float* ds_red_w    = (const float*)d_in[19];
  const float* emb         = (const float*)d_in[20];
  const float* hsw         = (const float*)d_in[21];
  const float* keyl        = (const float*)d_in[22];
  const float* queryl      = (const float*)d_in[23];
  const int*   rpi         = (const int*)d_in[24];

  char* ws = (char*)d_ws;
  short* wsw  = (short*)ws;                                  // 589824 B
  float* bias = (float*)(ws + 589824);                       // 65536 B
  short* ctx  = (short*)(ws + 655360);                       // 33554432 B
  short* lo   = (short*)(ws + 655360 + 33554432ULL);         // 33554432 B

  short* wv_bf = wsw;
  short* ow_bf = wsw + 16384;
  short* iw_bf = wsw + 32768;
  short* fw_bf = wsw + 98304;
  short* dw_bf = wsw + 163840;

  k_prep<<<289, 256, 0, stream>>>(value_w, out_dense_w, inter_w, ffn_out_w, ds_red_w,
                                  rel_tbl, cpb0_b, cpb0_w, cpb2_w, rpi, wsw, bias);
  k_attn<<<2048, 256, 0, stream>>>(hsw, queryl, keyl, logit_scale, value_b, wv_bf, bias, ctx);
  k_fuse<<<2048, 256, 0, stream>>>(ctx, ow_bf, out_dense_b, emb, ln_before_w, ln_before_b,
                                   iw_bf, inter_b, fw_bf, ffn_out_b,
                                   ln_after_w, ln_after_b, lo);
  k_merge<<<512, 256, 0, stream>>>(lo, dw_bf, ds_norm_w, ds_norm_b, (float*)d_out);
}

// Round 11
// 277.320 us; speedup vs baseline: 1.2774x; 1.2774x over previous
//
#include <hip/hip_runtime.h>

typedef __attribute__((ext_vector_type(4))) float f4;
typedef __attribute__((ext_vector_type(8))) short s8;
typedef __attribute__((ext_vector_type(4))) short s4;

__device__ __forceinline__ short f2bf(float f){
  unsigned u = __builtin_bit_cast(unsigned, f);
  u = (u + 0x7fffu + ((u >> 16) & 1u)) >> 16;
  return (short)u;
}
__device__ __forceinline__ float bf2f(short h){
  unsigned u = ((unsigned)(unsigned short)h) << 16;
  return __builtin_bit_cast(float, u);
}
__device__ __forceinline__ f4 mfma16(s8 a, s8 b, f4 c){
  return __builtin_amdgcn_mfma_f32_16x16x32_bf16(a, b, c, 0, 0, 0);
}
__device__ __forceinline__ s8 cfrag(const float* p){
  f4 a = *(const f4*)p; f4 b = *(const f4*)(p + 4);
  s8 t = {f2bf(a[0]), f2bf(a[1]), f2bf(a[2]), f2bf(a[3]),
          f2bf(b[0]), f2bf(b[1]), f2bf(b[2]), f2bf(b[3])};
  return t;
}
__device__ __forceinline__ s8 nfrag(const float* p){
  f4 a = *(const f4*)p; f4 b = *(const f4*)(p + 4);
  float ss = a[0]*a[0]+a[1]*a[1]+a[2]*a[2]+a[3]*a[3]
           + b[0]*b[0]+b[1]*b[1]+b[2]*b[2]+b[3]*b[3];
  ss += __shfl_xor(ss, 16); ss += __shfl_xor(ss, 32);
  float f = 1.0f / fmaxf(sqrtf(ss), 1e-12f);
  s8 t = {f2bf(a[0]*f), f2bf(a[1]*f), f2bf(a[2]*f), f2bf(a[3]*f),
          f2bf(b[0]*f), f2bf(b[1]*f), f2bf(b[2]*f), f2bf(b[3]*f)};
  return t;
}
#define SWZ(row) ((((row) ^ ((row) >> 3)) & 7) << 3)

// ---------------------------------------------------------------- k_prep
__global__ __launch_bounds__(256) void k_prep(
    const float* __restrict__ vw, const float* __restrict__ ow,
    const float* __restrict__ iw, const float* __restrict__ fw,
    const float* __restrict__ dw, const float* __restrict__ tbl,
    const float* __restrict__ c0b, const float* __restrict__ c0w,
    const float* __restrict__ c2w, const int* __restrict__ rpi,
    short* __restrict__ wsw, float* __restrict__ bias)
{
  if (blockIdx.x < 288) {
    int e0 = (blockIdx.x * 256 + threadIdx.x) * 4;
#pragma unroll
    for (int i = 0; i < 4; ++i) {
      int e = e0 + i;
      float v;
      if (e < 16384) v = vw[e];
      else if (e < 32768) v = ow[e - 16384];
      else if (e < 98304) v = iw[e - 32768];
      else if (e < 163840) v = fw[e - 98304];
      else v = dw[e - 163840];
      wsw[e] = f2bf(v);
    }
    return;
  }
  __shared__ float tb[900];
  __shared__ int orAcc;
  int tid = threadIdx.x;
  if (tid == 0) orAcc = 0;
  __syncthreads();
  int my = 0;
  for (int i = tid; i < 2048; i += 256) my |= rpi[2 * i + 1];
  atomicOr(&orAcc, my);
  if (tid < 225) {
    float t0 = tbl[tid * 2 + 0], t1 = tbl[tid * 2 + 1];
    float s0 = 0.f, s1 = 0.f, s2 = 0.f, s3 = 0.f;
    for (int j = 0; j < 512; ++j) {
      float hv = fmaxf(t0 * c0w[j * 2] + t1 * c0w[j * 2 + 1] + c0b[j], 0.f);
      s0 += hv * c2w[j];
      s1 += hv * c2w[512 + j];
      s2 += hv * c2w[1024 + j];
      s3 += hv * c2w[1536 + j];
    }
    tb[tid * 4 + 0] = s0; tb[tid * 4 + 1] = s1;
    tb[tid * 4 + 2] = s2; tb[tid * 4 + 3] = s3;
  }
  __syncthreads();
  bool i64 = (orAcc == 0);
#pragma unroll
  for (int it = 0; it < 64; ++it) {
    int e = it * 256 + tid;
    int rem = e & 4095;
    int h = e >> 12;
    int idx = i64 ? rpi[2 * rem] : rpi[rem];
    float v = tb[idx * 4 + h];
    bias[e] = 16.f / (1.f + __expf(-v));
  }
}

// ---------------------------------------------------------------- k_attn
// (proven form: hsw staged once, Vt/P reuse region, 48 KB, 3 blk/CU)
__global__ __launch_bounds__(256, 3) void k_attn(
    const float* __restrict__ hswp, const float* __restrict__ qg,
    const float* __restrict__ kg, const float* __restrict__ lsc,
    const float* __restrict__ vb, const short* __restrict__ wvb,
    const float* __restrict__ bias, short* __restrict__ ctx)
{
  __shared__ short lds[24576];
  const int bw = blockIdx.x, tid = threadIdx.x;
  const int lane = tid & 63, h = tid >> 6;
  const int r16 = lane & 15, b4 = lane >> 4;

  const float* qp = qg + ((size_t)bw * 4 + h) * 2048;
  const float* kp = kg + ((size_t)bw * 4 + h) * 2048;
  const float* hp = hswp + (size_t)bw * 8192;

  s8 qf[4], kf[4];
#pragma unroll
  for (int t = 0; t < 4; ++t) qf[t] = nfrag(qp + (t * 16 + r16) * 32 + b4 * 8);
#pragma unroll
  for (int t = 0; t < 4; ++t) kf[t] = nfrag(kp + (t * 16 + r16) * 32 + b4 * 8);

  {
    int row = tid >> 2, c0 = (tid & 3) * 32;
    const float* src = hp + row * 128 + c0;
    short* dst = &lds[row * 136 + c0];
#pragma unroll
    for (int j = 0; j < 4; ++j)
      *(s8*)(dst + j * 8) = cfrag(src + j * 8);
  }
  __syncthreads();

  f4 vac[2][4];
#pragma unroll
  for (int ct = 0; ct < 2; ++ct)
#pragma unroll
    for (int tt = 0; tt < 4; ++tt) vac[ct][tt] = (f4){0.f, 0.f, 0.f, 0.f};
#pragma unroll
  for (int ks = 0; ks < 4; ++ks) {
    s8 bfr[4];
#pragma unroll
    for (int tt = 0; tt < 4; ++tt)
      bfr[tt] = *(const s8*)&lds[(tt * 16 + r16) * 136 + ks * 32 + b4 * 8];
#pragma unroll
    for (int ct = 0; ct < 2; ++ct) {
      s8 af = *(const s8*)(wvb + (size_t)(h * 32 + ct * 16 + r16) * 128 + ks * 32 + b4 * 8);
#pragma unroll
      for (int tt = 0; tt < 4; ++tt)
        vac[ct][tt] = mfma16(af, bfr[tt], vac[ct][tt]);
    }
  }

  f4 sac[4][4];
#pragma unroll
  for (int a = 0; a < 4; ++a)
#pragma unroll
    for (int b = 0; b < 4; ++b) sac[a][b] = (f4){0.f, 0.f, 0.f, 0.f};
#pragma unroll
  for (int kt = 0; kt < 4; ++kt)
#pragma unroll
    for (int qt = 0; qt < 4; ++qt)
      sac[kt][qt] = mfma16(kf[kt], qf[qt], sac[kt][qt]);

  float scal = __expf(fminf(lsc[h], 4.60517019f));
  float rden[4];
#pragma unroll
  for (int qt = 0; qt < 4; ++qt) {
    float m = -1e30f;
#pragma unroll
    for (int kt = 0; kt < 4; ++kt) {
      f4 bv = *(const f4*)(bias + (h * 64 + qt * 16 + r16) * 64 + kt * 16 + b4 * 4);
#pragma unroll
      for (int r = 0; r < 4; ++r) {
        float sv = sac[kt][qt][r] * scal + bv[r];
        sac[kt][qt][r] = sv;
        m = fmaxf(m, sv);
      }
    }
    m = fmaxf(m, __shfl_xor(m, 16));
    m = fmaxf(m, __shfl_xor(m, 32));
    float sum = 0.f;
#pragma unroll
    for (int kt = 0; kt < 4; ++kt)
#pragma unroll
      for (int r = 0; r < 4; ++r) {
        float e = __expf(sac[kt][qt][r] - m);
        sac[kt][qt][r] = e;
        sum += e;
      }
    sum += __shfl_xor(sum, 16);
    sum += __shfl_xor(sum, 32);
    rden[qt] = 1.0f / sum;
  }

  __syncthreads();

  short* Vt = &lds[h * 6144];
  short* P  = &lds[h * 6144 + 2048];

#pragma unroll
  for (int ct = 0; ct < 2; ++ct)
#pragma unroll
    for (int r = 0; r < 4; ++r) {
      int row = ct * 16 + b4 * 4 + r;
      float bvl = vb[h * 32 + row];
#pragma unroll
      for (int tt = 0; tt < 4; ++tt) {
        int col = tt * 16 + r16;
        Vt[row * 64 + (col ^ SWZ(row))] = f2bf(vac[ct][tt][r] + bvl);
      }
    }
#pragma unroll
  for (int qt = 0; qt < 4; ++qt) {
    int q = qt * 16 + r16;
#pragma unroll
    for (int kt = 0; kt < 4; ++kt) {
      s4 p4;
#pragma unroll
      for (int r = 0; r < 4; ++r) p4[r] = f2bf(sac[kt][qt][r] * rden[qt]);
      *(s4*)&P[q * 64 + ((kt * 16 + b4 * 4) ^ SWZ(q))] = p4;
    }
  }

  f4 cac[2][4];
#pragma unroll
  for (int a = 0; a < 2; ++a)
#pragma unroll
    for (int b = 0; b < 4; ++b) cac[a][b] = (f4){0.f, 0.f, 0.f, 0.f};
#pragma unroll
  for (int ks = 0; ks < 2; ++ks) {
    s8 pf[4];
#pragma unroll
    for (int qt = 0; qt < 4; ++qt) {
      int q = qt * 16 + r16;
      pf[qt] = *(const s8*)&P[q * 64 + ((ks * 32 + b4 * 8) ^ SWZ(q))];
    }
#pragma unroll
    for (int dt = 0; dt < 2; ++dt) {
      int row = dt * 16 + r16;
      s8 vf = *(const s8*)&Vt[row * 64 + ((ks * 32 + b4 * 8) ^ SWZ(row))];
#pragma unroll
      for (int qt = 0; qt < 4; ++qt)
        cac[dt][qt] = mfma16(vf, pf[qt], cac[dt][qt]);
    }
  }
#pragma unroll
  for (int qt = 0; qt < 4; ++qt)
#pragma unroll
    for (int dt = 0; dt < 2; ++dt) {
      s4 o;
#pragma unroll
      for (int r = 0; r < 4; ++r) o[r] = f2bf(cac[dt][qt][r]);
      *(s4*)(ctx + (size_t)(bw * 64 + qt * 16 + r16) * 128 + h * 32 + dt * 16 + b4 * 4) = o;
    }
}

// ---------------------------------------------------------------- k_fuse
// EXACT 138-us structure incl. erff GELU (polynomial, VALU-pipelined —
// no trans-pipe latency chain; tanh-exp form stalled at 2 waves/SIMD).
__global__ __launch_bounds__(256, 2) void k_fuse(
    const short* __restrict__ ctx, const short* __restrict__ owb,
    const float* __restrict__ ob, const float* __restrict__ emb,
    const float* __restrict__ lnbw, const float* __restrict__ lnbb,
    const short* __restrict__ iwb, const float* __restrict__ ib,
    const short* __restrict__ fwb, const float* __restrict__ fb,
    const float* __restrict__ lnaw, const float* __restrict__ lnab,
    short* __restrict__ lo)
{
  __shared__ short Bs[128 * 136];      // 34816 B, shared weight panel
  __shared__ short hst[4][2184];       // 17472 B
  __shared__ short f1t[4][2184];       // 17472 B
  const int tid = threadIdx.x, lane = tid & 63, wv = tid >> 6;
  const int r16 = lane & 15, b4 = lane >> 4;
  const int obase = blockIdx.x * 64 + wv * 16;

  // ---- stage out_dense weights
#pragma unroll
  for (int it = 0; it < 8; ++it) {
    int ch = it * 256 + tid, n = ch >> 4, k8 = ch & 15;
    *(s8*)&Bs[n * 136 + k8 * 8] = *(const s8*)(owb + (size_t)n * 128 + k8 * 8);
  }
  __syncthreads();

  // ---- out-GEMM with inverse window-reverse gather
  int m = obase + r16;
  int bb = m >> 12, rimg = (m >> 6) & 63, cimg = m & 63;
  long tok = ((long)(bb * 64 + (rimg >> 3) * 8 + (cimg >> 3)) << 6)
           + (rimg & 7) * 8 + (cimg & 7);
  const short* ap = ctx + tok * 128;

  f4 acc[8];
#pragma unroll
  for (int nt = 0; nt < 8; ++nt) acc[nt] = (f4){0.f, 0.f, 0.f, 0.f};
#pragma unroll
  for (int ks = 0; ks < 4; ++ks) {
    s8 af = *(const s8*)(ap + ks * 32 + b4 * 8);
#pragma unroll
    for (int nt = 0; nt < 8; ++nt) {
      s8 bf = *(const s8*)&Bs[(nt * 16 + r16) * 136 + ks * 32 + b4 * 8];
      acc[nt] = mfma16(af, bf, acc[nt]);
    }
  }
  // LN_before + emb -> hst
#pragma unroll
  for (int r = 0; r < 4; ++r) {
    int t = b4 * 4 + r;
    long orow = obase + t;
    float x[8];
    float s = 0.f, s2 = 0.f;
#pragma unroll
    for (int nt = 0; nt < 8; ++nt) {
      int c = nt * 16 + r16;
      x[nt] = acc[nt][r] + ob[c];
      s += x[nt]; s2 += x[nt] * x[nt];
    }
    s += __shfl_xor(s, 1); s += __shfl_xor(s, 2); s += __shfl_xor(s, 4); s += __shfl_xor(s, 8);
    s2 += __shfl_xor(s2, 1); s2 += __shfl_xor(s2, 2); s2 += __shfl_xor(s2, 4); s2 += __shfl_xor(s2, 8);
    float mu = s * (1.f / 128.f);
    float var = s2 * (1.f / 128.f) - mu * mu;
    float rs = rsqrtf(var + 1e-5f);
#pragma unroll
    for (int nt = 0; nt < 8; ++nt) {
      int c = nt * 16 + r16;
      float y = (x[nt] - mu) * rs * lnbw[c] + lnbb[c] + emb[orow * 128 + c];
      hst[wv][t * 136 + c] = f2bf(y);
    }
  }

  // hs A-fragments (wave-private)
  s8 af1[4];
#pragma unroll
  for (int ks = 0; ks < 4; ++ks)
    af1[ks] = *(const s8*)&hst[wv][r16 * 136 + ks * 32 + b4 * 8];

  f4 acc2[8];
#pragma unroll
  for (int nt = 0; nt < 8; ++nt) acc2[nt] = (f4){0.f, 0.f, 0.f, 0.f};

  for (int cc = 0; cc < 4; ++cc) {
    int n0 = cc * 128;
    __syncthreads();
#pragma unroll
    for (int it = 0; it < 8; ++it) {
      int ch = it * 256 + tid, n = ch >> 4, k8 = ch & 15;
      *(s8*)&Bs[n * 136 + k8 * 8] = *(const s8*)(iwb + (size_t)(n0 + n) * 128 + k8 * 8);
    }
    __syncthreads();
    // ffn1 chunk
    f4 a1[8];
#pragma unroll
    for (int nt = 0; nt < 8; ++nt) a1[nt] = (f4){0.f, 0.f, 0.f, 0.f};
#pragma unroll
    for (int ks = 0; ks < 4; ++ks) {
#pragma unroll
      for (int nt = 0; nt < 8; ++nt) {
        s8 bf = *(const s8*)&Bs[(nt * 16 + r16) * 136 + ks * 32 + b4 * 8];
        a1[nt] = mfma16(af1[ks], bf, a1[nt]);
      }
    }
    // GELU (erff polynomial) -> f1t (wave-private)
#pragma unroll
    for (int r = 0; r < 4; ++r) {
      int t = b4 * 4 + r;
#pragma unroll
      for (int nt = 0; nt < 8; ++nt) {
        int c = nt * 16 + r16;
        float xg = a1[nt][r] + ib[n0 + c];
        float g = 0.5f * xg * (1.0f + erff(xg * 0.70710678118f));
        f1t[wv][t * 136 + c] = f2bf(g);
      }
    }
    __syncthreads();
#pragma unroll
    for (int it = 0; it < 8; ++it) {
      int ch = it * 256 + tid, n = ch >> 4, k8 = ch & 15;
      *(s8*)&Bs[n * 136 + k8 * 8] = *(const s8*)(fwb + (size_t)n * 512 + n0 + k8 * 8);
    }
    __syncthreads();
    // ffn2 partial K
#pragma unroll
    for (int ks = 0; ks < 4; ++ks) {
      s8 af2 = *(const s8*)&f1t[wv][r16 * 136 + ks * 32 + b4 * 8];
#pragma unroll
      for (int nt = 0; nt < 8; ++nt) {
        s8 bf = *(const s8*)&Bs[(nt * 16 + r16) * 136 + ks * 32 + b4 * 8];
        acc2[nt] = mfma16(af2, bf, acc2[nt]);
      }
    }
  }

  // ---- LN_after + residual (from hst) -> lo
#pragma unroll
  for (int r = 0; r < 4; ++r) {
    int t = b4 * 4 + r;
    long orow = obase + t;
    float x[8];
    float s = 0.f, s2 = 0.f;
#pragma unroll
    for (int nt = 0; nt < 8; ++nt) {
      int c = nt * 16 + r16;
      x[nt] = acc2[nt][r] + fb[c];
      s += x[nt]; s2 += x[nt] * x[nt];
    }
    s += __shfl_xor(s, 1); s += __shfl_xor(s, 2); s += __shfl_xor(s, 4); s += __shfl_xor(s, 8);
    s2 += __shfl_xor(s2, 1); s2 += __shfl_xor(s2, 2); s2 += __shfl_xor(s2, 4); s2 += __shfl_xor(s2, 8);
    float mu = s * (1.f / 128.f);
    float var = s2 * (1.f / 128.f) - mu * mu;
    float rs = rsqrtf(var + 1e-5f);
#pragma unroll
    for (int nt = 0; nt < 8; ++nt) {
      int c = nt * 16 + r16;
      float y = (x[nt] - mu) * rs * lnaw[c] + lnab[c] + bf2f(hst[wv][t * 136 + c]);
      lo[orow * 128 + c] = f2bf(y);
    }
  }
}

// ---------------------------------------------------------------- k_merge
__global__ __launch_bounds__(256) void k_merge(
    const short* __restrict__ lo, const short* __restrict__ dwb,
    const float* __restrict__ dsw, const float* __restrict__ dsb,
    float* __restrict__ out)
{
  __shared__ short Bs[256 * 136];
  const int tid = threadIdx.x;
  const int lane = tid & 63, wv = tid >> 6, r16 = lane & 15, b4 = lane >> 4;
  const int mrow = blockIdx.x * 64 + wv * 16;
  f4 acc[16];
#pragma unroll
  for (int nt = 0; nt < 16; ++nt) acc[nt] = (f4){0.f, 0.f, 0.f, 0.f};
  for (int kc = 0; kc < 4; ++kc) {
    if (kc) __syncthreads();
#pragma unroll
    for (int it = 0; it < 16; ++it) {
      int ch = it * 256 + tid, n = ch >> 4, k8 = ch & 15;
      *(s8*)&Bs[n * 136 + k8 * 8] = *(const s8*)(dwb + (size_t)n * 512 + kc * 128 + k8 * 8);
    }
    __syncthreads();
    int m = mrow + r16;
    int bb = m >> 10, p = m & 1023, ii = p >> 5, jj = p & 31;
    long row = (long)bb * 4096 + (2 * ii + (kc & 1)) * 64 + (2 * jj + (kc >> 1));
    const short* ap = lo + row * 128;
#pragma unroll
    for (int ks = 0; ks < 4; ++ks) {
      s8 af = *(const s8*)(ap + ks * 32 + b4 * 8);
#pragma unroll
      for (int nt = 0; nt < 16; ++nt) {
        s8 bf = *(const s8*)&Bs[(nt * 16 + r16) * 136 + ks * 32 + b4 * 8];
        acc[nt] = mfma16(af, bf, acc[nt]);
      }
    }
  }
#pragma unroll
  for (int r = 0; r < 4; ++r) {
    size_t m = mrow + b4 * 4 + r;
    float x[16];
    float s = 0.f, s2 = 0.f;
#pragma unroll
    for (int nt = 0; nt < 16; ++nt) {
      x[nt] = acc[nt][r];
      s += x[nt]; s2 += x[nt] * x[nt];
    }
    s += __shfl_xor(s, 1); s += __shfl_xor(s, 2); s += __shfl_xor(s, 4); s += __shfl_xor(s, 8);
    s2 += __shfl_xor(s2, 1); s2 += __shfl_xor(s2, 2); s2 += __shfl_xor(s2, 4); s2 += __shfl_xor(s2, 8);
    float mu = s * (1.f / 256.f);
    float var = s2 * (1.f / 256.f) - mu * mu;
    float rs = rsqrtf(var + 1e-5f);
#pragma unroll
    for (int nt = 0; nt < 16; ++nt) {
      int c = nt * 16 + r16;
      out[m * 256 + c] = (x[nt] - mu) * rs * dsw[c] + dsb[c];
    }
  }
}

// ---------------------------------------------------------------- launch
extern "C" void kernel_launch(void* const* d_in, const int* in_sizes, int n_in,
                              void* d_out, int out_size, void* d_ws, size_t ws_size,
                              hipStream_t stream)
{
  const float* out_dense_b = (const float*)d_in[0];
  const float* out_dense_w = (const float*)d_in[1];
  const float* rel_tbl     = (const float*)d_in[2];
  const float* cpb0_b      = (const float*)d_in[3];
  const float* cpb0_w      = (const float*)d_in[4];
  const float* cpb2_w      = (const float*)d_in[5];
  const float* value_b     = (const float*)d_in[6];
  const float* value_w     = (const float*)d_in[7];
  const float* logit_scale = (const float*)d_in[8];
  const float* inter_b     = (const float*)d_in[9];
  const float* inter_w     = (const float*)d_in[10];
  const float* ln_after_b  = (const float*)d_in[11];
  const float* ln_after_w  = (const float*)d_in[12];
  const float* ln_before_b = (const float*)d_in[13];
  const float* ln_before_w = (const float*)d_in[14];
  const float* ffn_out_b   = (const float*)d_in[15];
  const float* ffn_out_w   = (const float*)d_in[16];
  const float* ds_norm_b   = (const float*)d_in[17];
  const float* ds_norm_w   = (const float*)d_in[18];
  const float* ds_red_w    = (const float*)d_in[19];
  const float* emb         = (const float*)d_in[20];
  const float* hsw         = (const float*)d_in[21];
  const float* keyl        = (const float*)d_in[22];
  const float* queryl      = (const float*)d_in[23];
  const int*   rpi         = (const int*)d_in[24];

  char* ws = (char*)d_ws;
  short* wsw  = (short*)ws;                                  // 589824 B
  float* bias = (float*)(ws + 589824);                       // 65536 B
  short* ctx  = (short*)(ws + 655360);                       // 33554432 B
  short* lo   = (short*)(ws + 655360 + 33554432ULL);         // 33554432 B

  short* wv_bf = wsw;
  short* ow_bf = wsw + 16384;
  short* iw_bf = wsw + 32768;
  short* fw_bf = wsw + 98304;
  short* dw_bf = wsw + 163840;

  k_prep<<<289, 256, 0, stream>>>(value_w, out_dense_w, inter_w, ffn_out_w, ds_red_w,
                                  rel_tbl, cpb0_b, cpb0_w, cpb2_w, rpi, wsw, bias);
  k_attn<<<2048, 256, 0, stream>>>(hsw, queryl, keyl, logit_scale, value_b, wv_bf, bias, ctx);
  k_fuse<<<2048, 256, 0, stream>>>(ctx, ow_bf, out_dense_b, emb, ln_before_w, ln_before_b,
                                   iw_bf, inter_b, fw_bf, ffn_out_b,
                                   ln_after_w, ln_after_b, lo);
  k_merge<<<512, 256, 0, stream>>>(lo, dw_bf, ds_norm_w, ds_norm_b, (float*)d_out);
}

// Round 12
// 274.389 us; speedup vs baseline: 1.2910x; 1.0107x over previous
//
#include <hip/hip_runtime.h>

typedef __attribute__((ext_vector_type(4))) float f4;
typedef __attribute__((ext_vector_type(8))) short s8;
typedef __attribute__((ext_vector_type(4))) short s4;

__device__ __forceinline__ short f2bf(float f){
  unsigned u = __builtin_bit_cast(unsigned, f);
  u = (u + 0x7fffu + ((u >> 16) & 1u)) >> 16;
  return (short)u;
}
__device__ __forceinline__ float bf2f(short h){
  unsigned u = ((unsigned)(unsigned short)h) << 16;
  return __builtin_bit_cast(float, u);
}
__device__ __forceinline__ f4 mfma16(s8 a, s8 b, f4 c){
  return __builtin_amdgcn_mfma_f32_16x16x32_bf16(a, b, c, 0, 0, 0);
}
__device__ __forceinline__ s8 cfrag(const float* p){
  f4 a = *(const f4*)p; f4 b = *(const f4*)(p + 4);
  s8 t = {f2bf(a[0]), f2bf(a[1]), f2bf(a[2]), f2bf(a[3]),
          f2bf(b[0]), f2bf(b[1]), f2bf(b[2]), f2bf(b[3])};
  return t;
}
__device__ __forceinline__ s8 nfrag(const float* p){
  f4 a = *(const f4*)p; f4 b = *(const f4*)(p + 4);
  float ss = a[0]*a[0]+a[1]*a[1]+a[2]*a[2]+a[3]*a[3]
           + b[0]*b[0]+b[1]*b[1]+b[2]*b[2]+b[3]*b[3];
  ss += __shfl_xor(ss, 16); ss += __shfl_xor(ss, 32);
  float f = 1.0f / fmaxf(sqrtf(ss), 1e-12f);
  s8 t = {f2bf(a[0]*f), f2bf(a[1]*f), f2bf(a[2]*f), f2bf(a[3]*f),
          f2bf(b[0]*f), f2bf(b[1]*f), f2bf(b[2]*f), f2bf(b[3]*f)};
  return t;
}
#define SWZ(row) ((((row) ^ ((row) >> 3)) & 7) << 3)

// ---------------------------------------------------------------- k_prep
__global__ __launch_bounds__(256) void k_prep(
    const float* __restrict__ vw, const float* __restrict__ ow,
    const float* __restrict__ iw, const float* __restrict__ fw,
    const float* __restrict__ dw, const float* __restrict__ tbl,
    const float* __restrict__ c0b, const float* __restrict__ c0w,
    const float* __restrict__ c2w, const int* __restrict__ rpi,
    short* __restrict__ wsw, float* __restrict__ bias)
{
  if (blockIdx.x < 288) {
    int e0 = (blockIdx.x * 256 + threadIdx.x) * 4;
#pragma unroll
    for (int i = 0; i < 4; ++i) {
      int e = e0 + i;
      float v;
      if (e < 16384) v = vw[e];
      else if (e < 32768) v = ow[e - 16384];
      else if (e < 98304) v = iw[e - 32768];
      else if (e < 163840) v = fw[e - 98304];
      else v = dw[e - 163840];
      wsw[e] = f2bf(v);
    }
    return;
  }
  __shared__ float tb[900];
  __shared__ int orAcc;
  int tid = threadIdx.x;
  if (tid == 0) orAcc = 0;
  __syncthreads();
  int my = 0;
  for (int i = tid; i < 2048; i += 256) my |= rpi[2 * i + 1];
  atomicOr(&orAcc, my);
  if (tid < 225) {
    float t0 = tbl[tid * 2 + 0], t1 = tbl[tid * 2 + 1];
    float s0 = 0.f, s1 = 0.f, s2 = 0.f, s3 = 0.f;
    for (int j = 0; j < 512; ++j) {
      float hv = fmaxf(t0 * c0w[j * 2] + t1 * c0w[j * 2 + 1] + c0b[j], 0.f);
      s0 += hv * c2w[j];
      s1 += hv * c2w[512 + j];
      s2 += hv * c2w[1024 + j];
      s3 += hv * c2w[1536 + j];
    }
    tb[tid * 4 + 0] = s0; tb[tid * 4 + 1] = s1;
    tb[tid * 4 + 2] = s2; tb[tid * 4 + 3] = s3;
  }
  __syncthreads();
  bool i64 = (orAcc == 0);
#pragma unroll
  for (int it = 0; it < 64; ++it) {
    int e = it * 256 + tid;
    int rem = e & 4095;
    int h = e >> 12;
    int idx = i64 ? rpi[2 * rem] : rpi[rem];
    float v = tb[idx * 4 + h];
    bias[e] = 16.f / (1.f + __expf(-v));
  }
}

// ---------------------------------------------------------------- k_attn
// (proven form: hsw staged once, Vt/P reuse region, 48 KB, 3 blk/CU)
__global__ __launch_bounds__(256, 3) void k_attn(
    const float* __restrict__ hswp, const float* __restrict__ qg,
    const float* __restrict__ kg, const float* __restrict__ lsc,
    const float* __restrict__ vb, const short* __restrict__ wvb,
    const float* __restrict__ bias, short* __restrict__ ctx)
{
  __shared__ short lds[24576];
  const int bw = blockIdx.x, tid = threadIdx.x;
  const int lane = tid & 63, h = tid >> 6;
  const int r16 = lane & 15, b4 = lane >> 4;

  const float* qp = qg + ((size_t)bw * 4 + h) * 2048;
  const float* kp = kg + ((size_t)bw * 4 + h) * 2048;
  const float* hp = hswp + (size_t)bw * 8192;

  s8 qf[4], kf[4];
#pragma unroll
  for (int t = 0; t < 4; ++t) qf[t] = nfrag(qp + (t * 16 + r16) * 32 + b4 * 8);
#pragma unroll
  for (int t = 0; t < 4; ++t) kf[t] = nfrag(kp + (t * 16 + r16) * 32 + b4 * 8);

  {
    int row = tid >> 2, c0 = (tid & 3) * 32;
    const float* src = hp + row * 128 + c0;
    short* dst = &lds[row * 136 + c0];
#pragma unroll
    for (int j = 0; j < 4; ++j)
      *(s8*)(dst + j * 8) = cfrag(src + j * 8);
  }
  __syncthreads();

  f4 vac[2][4];
#pragma unroll
  for (int ct = 0; ct < 2; ++ct)
#pragma unroll
    for (int tt = 0; tt < 4; ++tt) vac[ct][tt] = (f4){0.f, 0.f, 0.f, 0.f};
#pragma unroll
  for (int ks = 0; ks < 4; ++ks) {
    s8 bfr[4];
#pragma unroll
    for (int tt = 0; tt < 4; ++tt)
      bfr[tt] = *(const s8*)&lds[(tt * 16 + r16) * 136 + ks * 32 + b4 * 8];
#pragma unroll
    for (int ct = 0; ct < 2; ++ct) {
      s8 af = *(const s8*)(wvb + (size_t)(h * 32 + ct * 16 + r16) * 128 + ks * 32 + b4 * 8);
#pragma unroll
      for (int tt = 0; tt < 4; ++tt)
        vac[ct][tt] = mfma16(af, bfr[tt], vac[ct][tt]);
    }
  }

  f4 sac[4][4];
#pragma unroll
  for (int a = 0; a < 4; ++a)
#pragma unroll
    for (int b = 0; b < 4; ++b) sac[a][b] = (f4){0.f, 0.f, 0.f, 0.f};
#pragma unroll
  for (int kt = 0; kt < 4; ++kt)
#pragma unroll
    for (int qt = 0; qt < 4; ++qt)
      sac[kt][qt] = mfma16(kf[kt], qf[qt], sac[kt][qt]);

  float scal = __expf(fminf(lsc[h], 4.60517019f));
  float rden[4];
#pragma unroll
  for (int qt = 0; qt < 4; ++qt) {
    float m = -1e30f;
#pragma unroll
    for (int kt = 0; kt < 4; ++kt) {
      f4 bv = *(const f4*)(bias + (h * 64 + qt * 16 + r16) * 64 + kt * 16 + b4 * 4);
#pragma unroll
      for (int r = 0; r < 4; ++r) {
        float sv = sac[kt][qt][r] * scal + bv[r];
        sac[kt][qt][r] = sv;
        m = fmaxf(m, sv);
      }
    }
    m = fmaxf(m, __shfl_xor(m, 16));
    m = fmaxf(m, __shfl_xor(m, 32));
    float sum = 0.f;
#pragma unroll
    for (int kt = 0; kt < 4; ++kt)
#pragma unroll
      for (int r = 0; r < 4; ++r) {
        float e = __expf(sac[kt][qt][r] - m);
        sac[kt][qt][r] = e;
        sum += e;
      }
    sum += __shfl_xor(sum, 16);
    sum += __shfl_xor(sum, 32);
    rden[qt] = 1.0f / sum;
  }

  __syncthreads();

  short* Vt = &lds[h * 6144];
  short* P  = &lds[h * 6144 + 2048];

#pragma unroll
  for (int ct = 0; ct < 2; ++ct)
#pragma unroll
    for (int r = 0; r < 4; ++r) {
      int row = ct * 16 + b4 * 4 + r;
      float bvl = vb[h * 32 + row];
#pragma unroll
      for (int tt = 0; tt < 4; ++tt) {
        int col = tt * 16 + r16;
        Vt[row * 64 + (col ^ SWZ(row))] = f2bf(vac[ct][tt][r] + bvl);
      }
    }
#pragma unroll
  for (int qt = 0; qt < 4; ++qt) {
    int q = qt * 16 + r16;
#pragma unroll
    for (int kt = 0; kt < 4; ++kt) {
      s4 p4;
#pragma unroll
      for (int r = 0; r < 4; ++r) p4[r] = f2bf(sac[kt][qt][r] * rden[qt]);
      *(s4*)&P[q * 64 + ((kt * 16 + b4 * 4) ^ SWZ(q))] = p4;
    }
  }

  f4 cac[2][4];
#pragma unroll
  for (int a = 0; a < 2; ++a)
#pragma unroll
    for (int b = 0; b < 4; ++b) cac[a][b] = (f4){0.f, 0.f, 0.f, 0.f};
#pragma unroll
  for (int ks = 0; ks < 2; ++ks) {
    s8 pf[4];
#pragma unroll
    for (int qt = 0; qt < 4; ++qt) {
      int q = qt * 16 + r16;
      pf[qt] = *(const s8*)&P[q * 64 + ((ks * 32 + b4 * 8) ^ SWZ(q))];
    }
#pragma unroll
    for (int dt = 0; dt < 2; ++dt) {
      int row = dt * 16 + r16;
      s8 vf = *(const s8*)&Vt[row * 64 + ((ks * 32 + b4 * 8) ^ SWZ(row))];
#pragma unroll
      for (int qt = 0; qt < 4; ++qt)
        cac[dt][qt] = mfma16(vf, pf[qt], cac[dt][qt]);
    }
  }
#pragma unroll
  for (int qt = 0; qt < 4; ++qt)
#pragma unroll
    for (int dt = 0; dt < 2; ++dt) {
      s4 o;
#pragma unroll
      for (int r = 0; r < 4; ++r) o[r] = f2bf(cac[dt][qt][r]);
      *(s4*)(ctx + (size_t)(bw * 64 + qt * 16 + r16) * 128 + h * 32 + dt * 16 + b4 * 4) = o;
    }
}

// ---------------------------------------------------------------- k_fuse
// 139-us erff structure + T14 async-stage: each weight panel is loaded
// into registers one full compute phase early; only reg->LDS writes sit
// between barriers (L2 latency hidden under MFMA/GELU phases).
__global__ __launch_bounds__(256, 2) void k_fuse(
    const short* __restrict__ ctx, const short* __restrict__ owb,
    const float* __restrict__ ob, const float* __restrict__ emb,
    const float* __restrict__ lnbw, const float* __restrict__ lnbb,
    const short* __restrict__ iwb, const float* __restrict__ ib,
    const short* __restrict__ fwb, const float* __restrict__ fb,
    const float* __restrict__ lnaw, const float* __restrict__ lnab,
    short* __restrict__ lo)
{
  __shared__ short Bs[128 * 136];      // 34816 B, shared weight panel
  __shared__ short hst[4][2184];       // 17472 B
  __shared__ short f1t[4][2184];       // 17472 B
  const int tid = threadIdx.x, lane = tid & 63, wv = tid >> 6;
  const int r16 = lane & 15, b4 = lane >> 4;
  const int obase = blockIdx.x * 64 + wv * 16;

  s8 pre[8];
  // prologue: owb panel -> regs -> Bs; then issue iwb chunk0 loads early
#pragma unroll
  for (int it = 0; it < 8; ++it) {
    int ch = it * 256 + tid;
    pre[it] = *(const s8*)(owb + (size_t)(ch >> 4) * 128 + (ch & 15) * 8);
  }
#pragma unroll
  for (int it = 0; it < 8; ++it) {
    int ch = it * 256 + tid;
    *(s8*)&Bs[(ch >> 4) * 136 + (ch & 15) * 8] = pre[it];
  }
#pragma unroll
  for (int it = 0; it < 8; ++it) {
    int ch = it * 256 + tid;
    pre[it] = *(const s8*)(iwb + (size_t)(ch >> 4) * 128 + (ch & 15) * 8);
  }
  __syncthreads();

  // ---- out-GEMM with inverse window-reverse gather
  int m = obase + r16;
  int bb = m >> 12, rimg = (m >> 6) & 63, cimg = m & 63;
  long tok = ((long)(bb * 64 + (rimg >> 3) * 8 + (cimg >> 3)) << 6)
           + (rimg & 7) * 8 + (cimg & 7);
  const short* ap = ctx + tok * 128;

  f4 acc[8];
#pragma unroll
  for (int nt = 0; nt < 8; ++nt) acc[nt] = (f4){0.f, 0.f, 0.f, 0.f};
#pragma unroll
  for (int ks = 0; ks < 4; ++ks) {
    s8 af = *(const s8*)(ap + ks * 32 + b4 * 8);
#pragma unroll
    for (int nt = 0; nt < 8; ++nt) {
      s8 bf = *(const s8*)&Bs[(nt * 16 + r16) * 136 + ks * 32 + b4 * 8];
      acc[nt] = mfma16(af, bf, acc[nt]);
    }
  }
  // LN_before + emb -> hst
#pragma unroll
  for (int r = 0; r < 4; ++r) {
    int t = b4 * 4 + r;
    long orow = obase + t;
    float x[8];
    float s = 0.f, s2 = 0.f;
#pragma unroll
    for (int nt = 0; nt < 8; ++nt) {
      int c = nt * 16 + r16;
      x[nt] = acc[nt][r] + ob[c];
      s += x[nt]; s2 += x[nt] * x[nt];
    }
    s += __shfl_xor(s, 1); s += __shfl_xor(s, 2); s += __shfl_xor(s, 4); s += __shfl_xor(s, 8);
    s2 += __shfl_xor(s2, 1); s2 += __shfl_xor(s2, 2); s2 += __shfl_xor(s2, 4); s2 += __shfl_xor(s2, 8);
    float mu = s * (1.f / 128.f);
    float var = s2 * (1.f / 128.f) - mu * mu;
    float rs = rsqrtf(var + 1e-5f);
#pragma unroll
    for (int nt = 0; nt < 8; ++nt) {
      int c = nt * 16 + r16;
      float y = (x[nt] - mu) * rs * lnbw[c] + lnbb[c] + emb[orow * 128 + c];
      hst[wv][t * 136 + c] = f2bf(y);
    }
  }

  // hs A-fragments (wave-private)
  s8 af1[4];
#pragma unroll
  for (int ks = 0; ks < 4; ++ks)
    af1[ks] = *(const s8*)&hst[wv][r16 * 136 + ks * 32 + b4 * 8];

  f4 acc2[8];
#pragma unroll
  for (int nt = 0; nt < 8; ++nt) acc2[nt] = (f4){0.f, 0.f, 0.f, 0.f};

  for (int cc = 0; cc < 4; ++cc) {
    int n0 = cc * 128;
    __syncthreads();                        // all waves done reading Bs
#pragma unroll
    for (int it = 0; it < 8; ++it) {        // write prefetched iwb chunk cc
      int ch = it * 256 + tid;
      *(s8*)&Bs[(ch >> 4) * 136 + (ch & 15) * 8] = pre[it];
    }
#pragma unroll
    for (int it = 0; it < 8; ++it) {        // issue fwb chunk cc loads
      int ch = it * 256 + tid;
      pre[it] = *(const s8*)(fwb + (size_t)(ch >> 4) * 512 + n0 + (ch & 15) * 8);
    }
    __syncthreads();
    // ffn1 chunk
    f4 a1[8];
#pragma unroll
    for (int nt = 0; nt < 8; ++nt) a1[nt] = (f4){0.f, 0.f, 0.f, 0.f};
#pragma unroll
    for (int ks = 0; ks < 4; ++ks) {
#pragma unroll
      for (int nt = 0; nt < 8; ++nt) {
        s8 bf = *(const s8*)&Bs[(nt * 16 + r16) * 136 + ks * 32 + b4 * 8];
        a1[nt] = mfma16(af1[ks], bf, a1[nt]);
      }
    }
    // GELU (erff polynomial) -> f1t (wave-private)
#pragma unroll
    for (int r = 0; r < 4; ++r) {
      int t = b4 * 4 + r;
#pragma unroll
      for (int nt = 0; nt < 8; ++nt) {
        int c = nt * 16 + r16;
        float xg = a1[nt][r] + ib[n0 + c];
        float g = 0.5f * xg * (1.0f + erff(xg * 0.70710678118f));
        f1t[wv][t * 136 + c] = f2bf(g);
      }
    }
    __syncthreads();                        // all waves done reading Bs (ffn1)
#pragma unroll
    for (int it = 0; it < 8; ++it) {        // write prefetched fwb chunk cc
      int ch = it * 256 + tid;
      *(s8*)&Bs[(ch >> 4) * 136 + (ch & 15) * 8] = pre[it];
    }
    if (cc < 3) {
#pragma unroll
      for (int it = 0; it < 8; ++it) {      // issue iwb chunk cc+1 loads
        int ch = it * 256 + tid;
        pre[it] = *(const s8*)(iwb + (size_t)(n0 + 128 + (ch >> 4)) * 128 + (ch & 15) * 8);
      }
    }
    __syncthreads();
    // ffn2 partial K
#pragma unroll
    for (int ks = 0; ks < 4; ++ks) {
      s8 af2 = *(const s8*)&f1t[wv][r16 * 136 + ks * 32 + b4 * 8];
#pragma unroll
      for (int nt = 0; nt < 8; ++nt) {
        s8 bf = *(const s8*)&Bs[(nt * 16 + r16) * 136 + ks * 32 + b4 * 8];
        acc2[nt] = mfma16(af2, bf, acc2[nt]);
      }
    }
  }

  // ---- LN_after + residual (from hst) -> lo
#pragma unroll
  for (int r = 0; r < 4; ++r) {
    int t = b4 * 4 + r;
    long orow = obase + t;
    float x[8];
    float s = 0.f, s2 = 0.f;
#pragma unroll
    for (int nt = 0; nt < 8; ++nt) {
      int c = nt * 16 + r16;
      x[nt] = acc2[nt][r] + fb[c];
      s += x[nt]; s2 += x[nt] * x[nt];
    }
    s += __shfl_xor(s, 1); s += __shfl_xor(s, 2); s += __shfl_xor(s, 4); s += __shfl_xor(s, 8);
    s2 += __shfl_xor(s2, 1); s2 += __shfl_xor(s2, 2); s2 += __shfl_xor(s2, 4); s2 += __shfl_xor(s2, 8);
    float mu = s * (1.f / 128.f);
    float var = s2 * (1.f / 128.f) - mu * mu;
    float rs = rsqrtf(var + 1e-5f);
#pragma unroll
    for (int nt = 0; nt < 8; ++nt) {
      int c = nt * 16 + r16;
      float y = (x[nt] - mu) * rs * lnaw[c] + lnab[c] + bf2f(hst[wv][t * 136 + c]);
      lo[orow * 128 + c] = f2bf(y);
    }
  }
}

// ---------------------------------------------------------------- k_merge
__global__ __launch_bounds__(256) void k_merge(
    const short* __restrict__ lo, const short* __restrict__ dwb,
    const float* __restrict__ dsw, const float* __restrict__ dsb,
    float* __restrict__ out)
{
  __shared__ short Bs[256 * 136];
  const int tid = threadIdx.x;
  const int lane = tid & 63, wv = tid >> 6, r16 = lane & 15, b4 = lane >> 4;
  const int mrow = blockIdx.x * 64 + wv * 16;
  f4 acc[16];
#pragma unroll
  for (int nt = 0; nt < 16; ++nt) acc[nt] = (f4){0.f, 0.f, 0.f, 0.f};
  for (int kc = 0; kc < 4; ++kc) {
    if (kc) __syncthreads();
#pragma unroll
    for (int it = 0; it < 16; ++it) {
      int ch = it * 256 + tid, n = ch >> 4, k8 = ch & 15;
      *(s8*)&Bs[n * 136 + k8 * 8] = *(const s8*)(dwb + (size_t)n * 512 + kc * 128 + k8 * 8);
    }
    __syncthreads();
    int m = mrow + r16;
    int bb = m >> 10, p = m & 1023, ii = p >> 5, jj = p & 31;
    long row = (long)bb * 4096 + (2 * ii + (kc & 1)) * 64 + (2 * jj + (kc >> 1));
    const short* ap = lo + row * 128;
#pragma unroll
    for (int ks = 0; ks < 4; ++ks) {
      s8 af = *(const s8*)(ap + ks * 32 + b4 * 8);
#pragma unroll
      for (int nt = 0; nt < 16; ++nt) {
        s8 bf = *(const s8*)&Bs[(nt * 16 + r16) * 136 + ks * 32 + b4 * 8];
        acc[nt] = mfma16(af, bf, acc[nt]);
      }
    }
  }
#pragma unroll
  for (int r = 0; r < 4; ++r) {
    size_t m = mrow + b4 * 4 + r;
    float x[16];
    float s = 0.f, s2 = 0.f;
#pragma unroll
    for (int nt = 0; nt < 16; ++nt) {
      x[nt] = acc[nt][r];
      s += x[nt]; s2 += x[nt] * x[nt];
    }
    s += __shfl_xor(s, 1); s += __shfl_xor(s, 2); s += __shfl_xor(s, 4); s += __shfl_xor(s, 8);
    s2 += __shfl_xor(s2, 1); s2 += __shfl_xor(s2, 2); s2 += __shfl_xor(s2, 4); s2 += __shfl_xor(s2, 8);
    float mu = s * (1.f / 256.f);
    float var = s2 * (1.f / 256.f) - mu * mu;
    float rs = rsqrtf(var + 1e-5f);
#pragma unroll
    for (int nt = 0; nt < 16; ++nt) {
      int c = nt * 16 + r16;
      out[m * 256 + c] = (x[nt] - mu) * rs * dsw[c] + dsb[c];
    }
  }
}

// ---------------------------------------------------------------- launch
extern "C" void kernel_launch(void* const* d_in, const int* in_sizes, int n_in,
                              void* d_out, int out_size, void* d_ws, size_t ws_size,
                              hipStream_t stream)
{
  const float* out_dense_b = (const float*)d_in[0];
  const float* out_dense_w = (const float*)d_in[1];
  const float* rel_tbl     = (const float*)d_in[2];
  const float* cpb0_b      = (const float*)d_in[3];
  const float* cpb0_w      = (const float*)d_in[4];
  const float* cpb2_w      = (const float*)d_in[5];
  const float* value_b     = (const float*)d_in[6];
  const float* value_w     = (const float*)d_in[7];
  const float* logit_scale = (const float*)d_in[8];
  const float* inter_b     = (const float*)d_in[9];
  const float* inter_w     = (const float*)d_in[10];
  const float* ln_after_b  = (const float*)d_in[11];
  const float* ln_after_w  = (const float*)d_in[12];
  const float* ln_before_b = (const float*)d_in[13];
  const float* ln_before_w = (const float*)d_in[14];
  const float* ffn_out_b   = (const float*)d_in[15];
  const float* ffn_out_w   = (const float*)d_in[16];
  const float* ds_norm_b   = (const float*)d_in[17];
  const float* ds_norm_w   = (const float*)d_in[18];
  const float* ds_red_w    = (const float*)d_in[19];
  const float* emb         = (const float*)d_in[20];
  const float* hsw         = (const float*)d_in[21];
  const float* keyl        = (const float*)d_in[22];
  const float* queryl      = (const float*)d_in[23];
  const int*   rpi         = (const int*)d_in[24];

  char* ws = (char*)d_ws;
  short* wsw  = (short*)ws;                                  // 589824 B
  float* bias = (float*)(ws + 589824);                       // 65536 B
  short* ctx  = (short*)(ws + 655360);                       // 33554432 B
  short* lo   = (short*)(ws + 655360 + 33554432ULL);         // 33554432 B

  short* wv_bf = wsw;
  short* ow_bf = wsw + 16384;
  short* iw_bf = wsw + 32768;
  short* fw_bf = wsw + 98304;
  short* dw_bf = wsw + 163840;

  k_prep<<<289, 256, 0, stream>>>(value_w, out_dense_w, inter_w, ffn_out_w, ds_red_w,
                                  rel_tbl, cpb0_b, cpb0_w, cpb2_w, rpi, wsw, bias);
  k_attn<<<2048, 256, 0, stream>>>(hsw, queryl, keyl, logit_scale, value_b, wv_bf, bias, ctx);
  k_fuse<<<2048, 256, 0, stream>>>(ctx, ow_bf, out_dense_b, emb, ln_before_w, ln_before_b,
                                   iw_bf, inter_b, fw_bf, ffn_out_b,
                                   ln_after_w, ln_after_b, lo);
  k_merge<<<512, 256, 0, stream>>>(lo, dw_bf, ds_norm_w, ds_norm_b, (float*)d_out);
}

// Round 13
// 265.453 us; speedup vs baseline: 1.3345x; 1.0337x over previous
//
#include <hip/hip_runtime.h>

typedef __attribute__((ext_vector_type(4))) float f4;
typedef __attribute__((ext_vector_type(8))) short s8;
typedef __attribute__((ext_vector_type(4))) short s4;

__device__ __forceinline__ short f2bf(float f){
  unsigned u = __builtin_bit_cast(unsigned, f);
  u = (u + 0x7fffu + ((u >> 16) & 1u)) >> 16;
  return (short)u;
}
__device__ __forceinline__ float bf2f(short h){
  unsigned u = ((unsigned)(unsigned short)h) << 16;
  return __builtin_bit_cast(float, u);
}
__device__ __forceinline__ f4 mfma16(s8 a, s8 b, f4 c){
  return __builtin_amdgcn_mfma_f32_16x16x32_bf16(a, b, c, 0, 0, 0);
}
__device__ __forceinline__ s8 cfrag(const float* p){
  f4 a = *(const f4*)p; f4 b = *(const f4*)(p + 4);
  s8 t = {f2bf(a[0]), f2bf(a[1]), f2bf(a[2]), f2bf(a[3]),
          f2bf(b[0]), f2bf(b[1]), f2bf(b[2]), f2bf(b[3])};
  return t;
}
__device__ __forceinline__ s8 nfrag(const float* p){
  f4 a = *(const f4*)p; f4 b = *(const f4*)(p + 4);
  float ss = a[0]*a[0]+a[1]*a[1]+a[2]*a[2]+a[3]*a[3]
           + b[0]*b[0]+b[1]*b[1]+b[2]*b[2]+b[3]*b[3];
  ss += __shfl_xor(ss, 16); ss += __shfl_xor(ss, 32);
  float f = 1.0f / fmaxf(sqrtf(ss), 1e-12f);
  s8 t = {f2bf(a[0]*f), f2bf(a[1]*f), f2bf(a[2]*f), f2bf(a[3]*f),
          f2bf(b[0]*f), f2bf(b[1]*f), f2bf(b[2]*f), f2bf(b[3]*f)};
  return t;
}
#define SWZ(row) ((((row) ^ ((row) >> 3)) & 7) << 3)

// ---------------------------------------------------------------- k_prep
__global__ __launch_bounds__(256) void k_prep(
    const float* __restrict__ vw, const float* __restrict__ ow,
    const float* __restrict__ iw, const float* __restrict__ fw,
    const float* __restrict__ dw, const float* __restrict__ tbl,
    const float* __restrict__ c0b, const float* __restrict__ c0w,
    const float* __restrict__ c2w, const int* __restrict__ rpi,
    short* __restrict__ wsw, float* __restrict__ bias)
{
  if (blockIdx.x < 288) {
    int e0 = (blockIdx.x * 256 + threadIdx.x) * 4;
#pragma unroll
    for (int i = 0; i < 4; ++i) {
      int e = e0 + i;
      float v;
      if (e < 16384) v = vw[e];
      else if (e < 32768) v = ow[e - 16384];
      else if (e < 98304) v = iw[e - 32768];
      else if (e < 163840) v = fw[e - 98304];
      else v = dw[e - 163840];
      wsw[e] = f2bf(v);
    }
    return;
  }
  __shared__ float tb[900];
  __shared__ int orAcc;
  int tid = threadIdx.x;
  if (tid == 0) orAcc = 0;
  __syncthreads();
  int my = 0;
  for (int i = tid; i < 2048; i += 256) my |= rpi[2 * i + 1];
  atomicOr(&orAcc, my);
  if (tid < 225) {
    float t0 = tbl[tid * 2 + 0], t1 = tbl[tid * 2 + 1];
    float s0 = 0.f, s1 = 0.f, s2 = 0.f, s3 = 0.f;
    for (int j = 0; j < 512; ++j) {
      float hv = fmaxf(t0 * c0w[j * 2] + t1 * c0w[j * 2 + 1] + c0b[j], 0.f);
      s0 += hv * c2w[j];
      s1 += hv * c2w[512 + j];
      s2 += hv * c2w[1024 + j];
      s3 += hv * c2w[1536 + j];
    }
    tb[tid * 4 + 0] = s0; tb[tid * 4 + 1] = s1;
    tb[tid * 4 + 2] = s2; tb[tid * 4 + 3] = s3;
  }
  __syncthreads();
  bool i64 = (orAcc == 0);
#pragma unroll
  for (int it = 0; it < 64; ++it) {
    int e = it * 256 + tid;
    int rem = e & 4095;
    int h = e >> 12;
    int idx = i64 ? rpi[2 * rem] : rpi[rem];
    float v = tb[idx * 4 + h];
    bias[e] = 16.f / (1.f + __expf(-v));
  }
}

// ---------------------------------------------------------------- k_attn
// (proven form: hsw staged once, Vt/P reuse region, 48 KB, 3 blk/CU)
__global__ __launch_bounds__(256, 3) void k_attn(
    const float* __restrict__ hswp, const float* __restrict__ qg,
    const float* __restrict__ kg, const float* __restrict__ lsc,
    const float* __restrict__ vb, const short* __restrict__ wvb,
    const float* __restrict__ bias, short* __restrict__ ctx)
{
  __shared__ short lds[24576];
  const int bw = blockIdx.x, tid = threadIdx.x;
  const int lane = tid & 63, h = tid >> 6;
  const int r16 = lane & 15, b4 = lane >> 4;

  const float* qp = qg + ((size_t)bw * 4 + h) * 2048;
  const float* kp = kg + ((size_t)bw * 4 + h) * 2048;
  const float* hp = hswp + (size_t)bw * 8192;

  s8 qf[4], kf[4];
#pragma unroll
  for (int t = 0; t < 4; ++t) qf[t] = nfrag(qp + (t * 16 + r16) * 32 + b4 * 8);
#pragma unroll
  for (int t = 0; t < 4; ++t) kf[t] = nfrag(kp + (t * 16 + r16) * 32 + b4 * 8);

  {
    int row = tid >> 2, c0 = (tid & 3) * 32;
    const float* src = hp + row * 128 + c0;
    short* dst = &lds[row * 136 + c0];
#pragma unroll
    for (int j = 0; j < 4; ++j)
      *(s8*)(dst + j * 8) = cfrag(src + j * 8);
  }
  __syncthreads();

  f4 vac[2][4];
#pragma unroll
  for (int ct = 0; ct < 2; ++ct)
#pragma unroll
    for (int tt = 0; tt < 4; ++tt) vac[ct][tt] = (f4){0.f, 0.f, 0.f, 0.f};
#pragma unroll
  for (int ks = 0; ks < 4; ++ks) {
    s8 bfr[4];
#pragma unroll
    for (int tt = 0; tt < 4; ++tt)
      bfr[tt] = *(const s8*)&lds[(tt * 16 + r16) * 136 + ks * 32 + b4 * 8];
#pragma unroll
    for (int ct = 0; ct < 2; ++ct) {
      s8 af = *(const s8*)(wvb + (size_t)(h * 32 + ct * 16 + r16) * 128 + ks * 32 + b4 * 8);
#pragma unroll
      for (int tt = 0; tt < 4; ++tt)
        vac[ct][tt] = mfma16(af, bfr[tt], vac[ct][tt]);
    }
  }

  f4 sac[4][4];
#pragma unroll
  for (int a = 0; a < 4; ++a)
#pragma unroll
    for (int b = 0; b < 4; ++b) sac[a][b] = (f4){0.f, 0.f, 0.f, 0.f};
#pragma unroll
  for (int kt = 0; kt < 4; ++kt)
#pragma unroll
    for (int qt = 0; qt < 4; ++qt)
      sac[kt][qt] = mfma16(kf[kt], qf[qt], sac[kt][qt]);

  float scal = __expf(fminf(lsc[h], 4.60517019f));
  float rden[4];
#pragma unroll
  for (int qt = 0; qt < 4; ++qt) {
    float m = -1e30f;
#pragma unroll
    for (int kt = 0; kt < 4; ++kt) {
      f4 bv = *(const f4*)(bias + (h * 64 + qt * 16 + r16) * 64 + kt * 16 + b4 * 4);
#pragma unroll
      for (int r = 0; r < 4; ++r) {
        float sv = sac[kt][qt][r] * scal + bv[r];
        sac[kt][qt][r] = sv;
        m = fmaxf(m, sv);
      }
    }
    m = fmaxf(m, __shfl_xor(m, 16));
    m = fmaxf(m, __shfl_xor(m, 32));
    float sum = 0.f;
#pragma unroll
    for (int kt = 0; kt < 4; ++kt)
#pragma unroll
      for (int r = 0; r < 4; ++r) {
        float e = __expf(sac[kt][qt][r] - m);
        sac[kt][qt][r] = e;
        sum += e;
      }
    sum += __shfl_xor(sum, 16);
    sum += __shfl_xor(sum, 32);
    rden[qt] = 1.0f / sum;
  }

  __syncthreads();

  short* Vt = &lds[h * 6144];
  short* P  = &lds[h * 6144 + 2048];

#pragma unroll
  for (int ct = 0; ct < 2; ++ct)
#pragma unroll
    for (int r = 0; r < 4; ++r) {
      int row = ct * 16 + b4 * 4 + r;
      float bvl = vb[h * 32 + row];
#pragma unroll
      for (int tt = 0; tt < 4; ++tt) {
        int col = tt * 16 + r16;
        Vt[row * 64 + (col ^ SWZ(row))] = f2bf(vac[ct][tt][r] + bvl);
      }
    }
#pragma unroll
  for (int qt = 0; qt < 4; ++qt) {
    int q = qt * 16 + r16;
#pragma unroll
    for (int kt = 0; kt < 4; ++kt) {
      s4 p4;
#pragma unroll
      for (int r = 0; r < 4; ++r) p4[r] = f2bf(sac[kt][qt][r] * rden[qt]);
      *(s4*)&P[q * 64 + ((kt * 16 + b4 * 4) ^ SWZ(q))] = p4;
    }
  }

  f4 cac[2][4];
#pragma unroll
  for (int a = 0; a < 2; ++a)
#pragma unroll
    for (int b = 0; b < 4; ++b) cac[a][b] = (f4){0.f, 0.f, 0.f, 0.f};
#pragma unroll
  for (int ks = 0; ks < 2; ++ks) {
    s8 pf[4];
#pragma unroll
    for (int qt = 0; qt < 4; ++qt) {
      int q = qt * 16 + r16;
      pf[qt] = *(const s8*)&P[q * 64 + ((ks * 32 + b4 * 8) ^ SWZ(q))];
    }
#pragma unroll
    for (int dt = 0; dt < 2; ++dt) {
      int row = dt * 16 + r16;
      s8 vf = *(const s8*)&Vt[row * 64 + ((ks * 32 + b4 * 8) ^ SWZ(row))];
#pragma unroll
      for (int qt = 0; qt < 4; ++qt)
        cac[dt][qt] = mfma16(vf, pf[qt], cac[dt][qt]);
    }
  }
#pragma unroll
  for (int qt = 0; qt < 4; ++qt)
#pragma unroll
    for (int dt = 0; dt < 2; ++dt) {
      s4 o;
#pragma unroll
      for (int r = 0; r < 4; ++r) o[r] = f2bf(cac[dt][qt][r]);
      *(s4*)(ctx + (size_t)(bw * 64 + qt * 16 + r16) * 128 + h * 32 + dt * 16 + b4 * 4) = o;
    }
}

// ---------------------------------------------------------------- k_fuse
// erff base (proven 139 us) + occupancy 2->3 blk/CU: residual hs is
// round-tripped through lo (global, L2-hot, same-thread RAW), so the
// wave-private LDS tile is reused for f1. LDS 52.3 KB. No reg prefetch
// (proven neutral; keeps VGPR under the (256,3) cap -> no spill).
__global__ __launch_bounds__(256, 3) void k_fuse(
    const short* __restrict__ ctx, const short* __restrict__ owb,
    const float* __restrict__ ob, const float* __restrict__ emb,
    const float* __restrict__ lnbw, const float* __restrict__ lnbb,
    const short* __restrict__ iwb, const float* __restrict__ ib,
    const short* __restrict__ fwb, const float* __restrict__ fb,
    const float* __restrict__ lnaw, const float* __restrict__ lnab,
    short* __restrict__ lo)
{
  __shared__ short Bs[128 * 136];      // 34816 B, shared weight panel
  __shared__ short ht[4][2184];        // 17472 B: hs tile, then f1 tile
  const int tid = threadIdx.x, lane = tid & 63, wv = tid >> 6;
  const int r16 = lane & 15, b4 = lane >> 4;
  const int obase = blockIdx.x * 64 + wv * 16;

  // ---- stage out_dense weights
#pragma unroll
  for (int it = 0; it < 8; ++it) {
    int ch = it * 256 + tid, n = ch >> 4, k8 = ch & 15;
    *(s8*)&Bs[n * 136 + k8 * 8] = *(const s8*)(owb + (size_t)n * 128 + k8 * 8);
  }
  __syncthreads();

  // ---- out-GEMM with inverse window-reverse gather
  int m = obase + r16;
  int bb = m >> 12, rimg = (m >> 6) & 63, cimg = m & 63;
  long tok = ((long)(bb * 64 + (rimg >> 3) * 8 + (cimg >> 3)) << 6)
           + (rimg & 7) * 8 + (cimg & 7);
  const short* ap = ctx + tok * 128;

  f4 acc[8];
#pragma unroll
  for (int nt = 0; nt < 8; ++nt) acc[nt] = (f4){0.f, 0.f, 0.f, 0.f};
#pragma unroll
  for (int ks = 0; ks < 4; ++ks) {
    s8 af = *(const s8*)(ap + ks * 32 + b4 * 8);
#pragma unroll
    for (int nt = 0; nt < 8; ++nt) {
      s8 bf = *(const s8*)&Bs[(nt * 16 + r16) * 136 + ks * 32 + b4 * 8];
      acc[nt] = mfma16(af, bf, acc[nt]);
    }
  }
  // LN_before + emb -> ht (for af1) AND lo (residual keep, global L2)
#pragma unroll
  for (int r = 0; r < 4; ++r) {
    int t = b4 * 4 + r;
    long orow = obase + t;
    float x[8];
    float s = 0.f, s2 = 0.f;
#pragma unroll
    for (int nt = 0; nt < 8; ++nt) {
      int c = nt * 16 + r16;
      x[nt] = acc[nt][r] + ob[c];
      s += x[nt]; s2 += x[nt] * x[nt];
    }
    s += __shfl_xor(s, 1); s += __shfl_xor(s, 2); s += __shfl_xor(s, 4); s += __shfl_xor(s, 8);
    s2 += __shfl_xor(s2, 1); s2 += __shfl_xor(s2, 2); s2 += __shfl_xor(s2, 4); s2 += __shfl_xor(s2, 8);
    float mu = s * (1.f / 128.f);
    float var = s2 * (1.f / 128.f) - mu * mu;
    float rs = rsqrtf(var + 1e-5f);
#pragma unroll
    for (int nt = 0; nt < 8; ++nt) {
      int c = nt * 16 + r16;
      float y = (x[nt] - mu) * rs * lnbw[c] + lnbb[c] + emb[orow * 128 + c];
      short yb = f2bf(y);
      ht[wv][t * 136 + c] = yb;
      lo[orow * 128 + c] = yb;
    }
  }

  // hs A-fragments (wave-private; ht dead for hs after this)
  s8 af1[4];
#pragma unroll
  for (int ks = 0; ks < 4; ++ks)
    af1[ks] = *(const s8*)&ht[wv][r16 * 136 + ks * 32 + b4 * 8];

  f4 acc2[8];
#pragma unroll
  for (int nt = 0; nt < 8; ++nt) acc2[nt] = (f4){0.f, 0.f, 0.f, 0.f};

  for (int cc = 0; cc < 4; ++cc) {
    int n0 = cc * 128;
    __syncthreads();
#pragma unroll
    for (int it = 0; it < 8; ++it) {
      int ch = it * 256 + tid, n = ch >> 4, k8 = ch & 15;
      *(s8*)&Bs[n * 136 + k8 * 8] = *(const s8*)(iwb + (size_t)(n0 + n) * 128 + k8 * 8);
    }
    __syncthreads();
    // ffn1 chunk
    f4 a1[8];
#pragma unroll
    for (int nt = 0; nt < 8; ++nt) a1[nt] = (f4){0.f, 0.f, 0.f, 0.f};
#pragma unroll
    for (int ks = 0; ks < 4; ++ks) {
#pragma unroll
      for (int nt = 0; nt < 8; ++nt) {
        s8 bf = *(const s8*)&Bs[(nt * 16 + r16) * 136 + ks * 32 + b4 * 8];
        a1[nt] = mfma16(af1[ks], bf, a1[nt]);
      }
    }
    // GELU (erff polynomial) -> ht (reused as f1 tile; wave-private)
#pragma unroll
    for (int r = 0; r < 4; ++r) {
      int t = b4 * 4 + r;
#pragma unroll
      for (int nt = 0; nt < 8; ++nt) {
        int c = nt * 16 + r16;
        float xg = a1[nt][r] + ib[n0 + c];
        float g = 0.5f * xg * (1.0f + erff(xg * 0.70710678118f));
        ht[wv][t * 136 + c] = f2bf(g);
      }
    }
    __syncthreads();
#pragma unroll
    for (int it = 0; it < 8; ++it) {
      int ch = it * 256 + tid, n = ch >> 4, k8 = ch & 15;
      *(s8*)&Bs[n * 136 + k8 * 8] = *(const s8*)(fwb + (size_t)n * 512 + n0 + k8 * 8);
    }
    __syncthreads();
    // ffn2 partial K
#pragma unroll
    for (int ks = 0; ks < 4; ++ks) {
      s8 af2 = *(const s8*)&ht[wv][r16 * 136 + ks * 32 + b4 * 8];
#pragma unroll
      for (int nt = 0; nt < 8; ++nt) {
        s8 bf = *(const s8*)&Bs[(nt * 16 + r16) * 136 + ks * 32 + b4 * 8];
        acc2[nt] = mfma16(af2, bf, acc2[nt]);
      }
    }
  }

  // ---- LN_after + residual (read back from lo, same-thread RAW) -> lo
#pragma unroll
  for (int r = 0; r < 4; ++r) {
    int t = b4 * 4 + r;
    long orow = obase + t;
    float x[8], res[8];
    float s = 0.f, s2 = 0.f;
#pragma unroll
    for (int nt = 0; nt < 8; ++nt) {
      int c = nt * 16 + r16;
      res[nt] = bf2f(lo[orow * 128 + c]);
      x[nt] = acc2[nt][r] + fb[c];
      s += x[nt]; s2 += x[nt] * x[nt];
    }
    s += __shfl_xor(s, 1); s += __shfl_xor(s, 2); s += __shfl_xor(s, 4); s += __shfl_xor(s, 8);
    s2 += __shfl_xor(s2, 1); s2 += __shfl_xor(s2, 2); s2 += __shfl_xor(s2, 4); s2 += __shfl_xor(s2, 8);
    float mu = s * (1.f / 128.f);
    float var = s2 * (1.f / 128.f) - mu * mu;
    float rs = rsqrtf(var + 1e-5f);
#pragma unroll
    for (int nt = 0; nt < 8; ++nt) {
      int c = nt * 16 + r16;
      float y = (x[nt] - mu) * rs * lnaw[c] + lnab[c] + res[nt];
      lo[orow * 128 + c] = f2bf(y);
    }
  }
}

// ---------------------------------------------------------------- k_merge
__global__ __launch_bounds__(256) void k_merge(
    const short* __restrict__ lo, const short* __restrict__ dwb,
    const float* __restrict__ dsw, const float* __restrict__ dsb,
    float* __restrict__ out)
{
  __shared__ short Bs[256 * 136];
  const int tid = threadIdx.x;
  const int lane = tid & 63, wv = tid >> 6, r16 = lane & 15, b4 = lane >> 4;
  const int mrow = blockIdx.x * 64 + wv * 16;
  f4 acc[16];
#pragma unroll
  for (int nt = 0; nt < 16; ++nt) acc[nt] = (f4){0.f, 0.f, 0.f, 0.f};
  for (int kc = 0; kc < 4; ++kc) {
    if (kc) __syncthreads();
#pragma unroll
    for (int it = 0; it < 16; ++it) {
      int ch = it * 256 + tid, n = ch >> 4, k8 = ch & 15;
      *(s8*)&Bs[n * 136 + k8 * 8] = *(const s8*)(dwb + (size_t)n * 512 + kc * 128 + k8 * 8);
    }
    __syncthreads();
    int m = mrow + r16;
    int bb = m >> 10, p = m & 1023, ii = p >> 5, jj = p & 31;
    long row = (long)bb * 4096 + (2 * ii + (kc & 1)) * 64 + (2 * jj + (kc >> 1));
    const short* ap = lo + row * 128;
#pragma unroll
    for (int ks = 0; ks < 4; ++ks) {
      s8 af = *(const s8*)(ap + ks * 32 + b4 * 8);
#pragma unroll
      for (int nt = 0; nt < 16; ++nt) {
        s8 bf = *(const s8*)&Bs[(nt * 16 + r16) * 136 + ks * 32 + b4 * 8];
        acc[nt] = mfma16(af, bf, acc[nt]);
      }
    }
  }
#pragma unroll
  for (int r = 0; r < 4; ++r) {
    size_t m = mrow + b4 * 4 + r;
    float x[16];
    float s = 0.f, s2 = 0.f;
#pragma unroll
    for (int nt = 0; nt < 16; ++nt) {
      x[nt] = acc[nt][r];
      s += x[nt]; s2 += x[nt] * x[nt];
    }
    s += __shfl_xor(s, 1); s += __shfl_xor(s, 2); s += __shfl_xor(s, 4); s += __shfl_xor(s, 8);
    s2 += __shfl_xor(s2, 1); s2 += __shfl_xor(s2, 2); s2 += __shfl_xor(s2, 4); s2 += __shfl_xor(s2, 8);
    float mu = s * (1.f / 256.f);
    float var = s2 * (1.f / 256.f) - mu * mu;
    float rs = rsqrtf(var + 1e-5f);
#pragma unroll
    for (int nt = 0; nt < 16; ++nt) {
      int c = nt * 16 + r16;
      out[m * 256 + c] = (x[nt] - mu) * rs * dsw[c] + dsb[c];
    }
  }
}

// ---------------------------------------------------------------- launch
extern "C" void kernel_launch(void* const* d_in, const int* in_sizes, int n_in,
                              void* d_out, int out_size, void* d_ws, size_t ws_size,
                              hipStream_t stream)
{
  const float* out_dense_b = (const float*)d_in[0];
  const float* out_dense_w = (const float*)d_in[1];
  const float* rel_tbl     = (const float*)d_in[2];
  const float* cpb0_b      = (const float*)d_in[3];
  const float* cpb0_w      = (const float*)d_in[4];
  const float* cpb2_w      = (const float*)d_in[5];
  const float* value_b     = (const float*)d_in[6];
  const float* value_w     = (const float*)d_in[7];
  const float* logit_scale = (const float*)d_in[8];
  const float* inter_b     = (const float*)d_in[9];
  const float* inter_w     = (const float*)d_in[10];
  const float* ln_after_b  = (const float*)d_in[11];
  const float* ln_after_w  = (const float*)d_in[12];
  const float* ln_before_b = (const float*)d_in[13];
  const float* ln_before_w = (const float*)d_in[14];
  const float* ffn_out_b   = (const float*)d_in[15];
  const float* ffn_out_w   = (const float*)d_in[16];
  const float* ds_norm_b   = (const float*)d_in[17];
  const float* ds_norm_w   = (const float*)d_in[18];
  const float* ds_red_w    = (const float*)d_in[19];
  const float* emb         = (const float*)d_in[20];
  const float* hsw         = (const float*)d_in[21];
  const float* keyl        = (const float*)d_in[22];
  const float* queryl      = (const float*)d_in[23];
  const int*   rpi         = (const int*)d_in[24];

  char* ws = (char*)d_ws;
  short* wsw  = (short*)ws;                                  // 589824 B
  float* bias = (float*)(ws + 589824);                       // 65536 B
  short* ctx  = (short*)(ws + 655360);                       // 33554432 B
  short* lo   = (short*)(ws + 655360 + 33554432ULL);         // 33554432 B

  short* wv_bf = wsw;
  short* ow_bf = wsw + 16384;
  short* iw_bf = wsw + 32768;
  short* fw_bf = wsw + 98304;
  short* dw_bf = wsw + 163840;

  k_prep<<<289, 256, 0, stream>>>(value_w, out_dense_w, inter_w, ffn_out_w, ds_red_w,
                                  rel_tbl, cpb0_b, cpb0_w, cpb2_w, rpi, wsw, bias);
  k_attn<<<2048, 256, 0, stream>>>(hsw, queryl, keyl, logit_scale, value_b, wv_bf, bias, ctx);
  k_fuse<<<2048, 256, 0, stream>>>(ctx, ow_bf, out_dense_b, emb, ln_before_w, ln_before_b,
                                   iw_bf, inter_b, fw_bf, ffn_out_b,
                                   ln_after_w, ln_after_b, lo);
  k_merge<<<512, 256, 0, stream>>>(lo, dw_bf, ds_norm_w, ds_norm_b, (float*)d_out);
}

// Round 14
// 228.788 us; speedup vs baseline: 1.5484x; 1.1603x over previous
//
#include <hip/hip_runtime.h>

typedef __attribute__((ext_vector_type(4))) float f4;
typedef __attribute__((ext_vector_type(8))) short s8;
typedef __attribute__((ext_vector_type(4))) short s4;

__device__ __forceinline__ short f2bf(float f){
  unsigned u = __builtin_bit_cast(unsigned, f);
  u = (u + 0x7fffu + ((u >> 16) & 1u)) >> 16;
  return (short)u;
}
__device__ __forceinline__ float bf2f(short h){
  unsigned u = ((unsigned)(unsigned short)h) << 16;
  return __builtin_bit_cast(float, u);
}
__device__ __forceinline__ f4 mfma16(s8 a, s8 b, f4 c){
  return __builtin_amdgcn_mfma_f32_16x16x32_bf16(a, b, c, 0, 0, 0);
}
__device__ __forceinline__ s8 cfrag(const float* p){
  f4 a = *(const f4*)p; f4 b = *(const f4*)(p + 4);
  s8 t = {f2bf(a[0]), f2bf(a[1]), f2bf(a[2]), f2bf(a[3]),
          f2bf(b[0]), f2bf(b[1]), f2bf(b[2]), f2bf(b[3])};
  return t;
}
__device__ __forceinline__ s8 nfrag(const float* p){
  f4 a = *(const f4*)p; f4 b = *(const f4*)(p + 4);
  float ss = a[0]*a[0]+a[1]*a[1]+a[2]*a[2]+a[3]*a[3]
           + b[0]*b[0]+b[1]*b[1]+b[2]*b[2]+b[3]*b[3];
  ss += __shfl_xor(ss, 16); ss += __shfl_xor(ss, 32);
  float f = 1.0f / fmaxf(sqrtf(ss), 1e-12f);
  s8 t = {f2bf(a[0]*f), f2bf(a[1]*f), f2bf(a[2]*f), f2bf(a[3]*f),
          f2bf(b[0]*f), f2bf(b[1]*f), f2bf(b[2]*f), f2bf(b[3]*f)};
  return t;
}
#define SWZ(row) ((((row) ^ ((row) >> 3)) & 7) << 3)

// ---------------------------------------------------------------- k_prep
__global__ __launch_bounds__(256) void k_prep(
    const float* __restrict__ vw, const float* __restrict__ ow,
    const float* __restrict__ iw, const float* __restrict__ fw,
    const float* __restrict__ dw, const float* __restrict__ tbl,
    const float* __restrict__ c0b, const float* __restrict__ c0w,
    const float* __restrict__ c2w, const int* __restrict__ rpi,
    short* __restrict__ wsw, float* __restrict__ bias)
{
  if (blockIdx.x < 288) {
    int e0 = (blockIdx.x * 256 + threadIdx.x) * 4;
#pragma unroll
    for (int i = 0; i < 4; ++i) {
      int e = e0 + i;
      float v;
      if (e < 16384) v = vw[e];
      else if (e < 32768) v = ow[e - 16384];
      else if (e < 98304) v = iw[e - 32768];
      else if (e < 163840) v = fw[e - 98304];
      else v = dw[e - 163840];
      wsw[e] = f2bf(v);
    }
    return;
  }
  __shared__ float tb[900];
  __shared__ float cw[1024], cb[512], c2l[2048];
  __shared__ int orAcc;
  int tid = threadIdx.x;
  if (tid == 0) orAcc = 0;
  // stage CPB MLP weights into LDS (removes L2 latency from the serial loop)
  for (int i = tid; i < 1024; i += 256) cw[i] = c0w[i];
  for (int i = tid; i < 512;  i += 256) cb[i] = c0b[i];
  for (int i = tid; i < 2048; i += 256) c2l[i] = c2w[i];
  __syncthreads();
  int my = 0;
  for (int i = tid; i < 2048; i += 256) my |= rpi[2 * i + 1];
  atomicOr(&orAcc, my);
  if (tid < 225) {
    float t0 = tbl[tid * 2 + 0], t1 = tbl[tid * 2 + 1];
    float s0 = 0.f, s1 = 0.f, s2 = 0.f, s3 = 0.f;
    for (int j = 0; j < 512; ++j) {
      float hv = fmaxf(t0 * cw[j * 2] + t1 * cw[j * 2 + 1] + cb[j], 0.f);
      s0 += hv * c2l[j];
      s1 += hv * c2l[512 + j];
      s2 += hv * c2l[1024 + j];
      s3 += hv * c2l[1536 + j];
    }
    tb[tid * 4 + 0] = s0; tb[tid * 4 + 1] = s1;
    tb[tid * 4 + 2] = s2; tb[tid * 4 + 3] = s3;
  }
  __syncthreads();
  bool i64 = (orAcc == 0);
#pragma unroll
  for (int it = 0; it < 64; ++it) {
    int e = it * 256 + tid;
    int rem = e & 4095;
    int h = e >> 12;
    int idx = i64 ? rpi[2 * rem] : rpi[rem];
    float v = tb[idx * 4 + h];
    bias[e] = 16.f / (1.f + __expf(-v));
  }
}

// ---------------------------------------------------------------- k_attn
// (proven form: hsw staged once, Vt/P reuse region, 48 KB, 3 blk/CU)
__global__ __launch_bounds__(256, 3) void k_attn(
    const float* __restrict__ hswp, const float* __restrict__ qg,
    const float* __restrict__ kg, const float* __restrict__ lsc,
    const float* __restrict__ vb, const short* __restrict__ wvb,
    const float* __restrict__ bias, short* __restrict__ ctx)
{
  __shared__ short lds[24576];
  const int bw = blockIdx.x, tid = threadIdx.x;
  const int lane = tid & 63, h = tid >> 6;
  const int r16 = lane & 15, b4 = lane >> 4;

  const float* qp = qg + ((size_t)bw * 4 + h) * 2048;
  const float* kp = kg + ((size_t)bw * 4 + h) * 2048;
  const float* hp = hswp + (size_t)bw * 8192;

  s8 qf[4], kf[4];
#pragma unroll
  for (int t = 0; t < 4; ++t) qf[t] = nfrag(qp + (t * 16 + r16) * 32 + b4 * 8);
#pragma unroll
  for (int t = 0; t < 4; ++t) kf[t] = nfrag(kp + (t * 16 + r16) * 32 + b4 * 8);

  {
    int row = tid >> 2, c0 = (tid & 3) * 32;
    const float* src = hp + row * 128 + c0;
    short* dst = &lds[row * 136 + c0];
#pragma unroll
    for (int j = 0; j < 4; ++j)
      *(s8*)(dst + j * 8) = cfrag(src + j * 8);
  }
  __syncthreads();

  f4 vac[2][4];
#pragma unroll
  for (int ct = 0; ct < 2; ++ct)
#pragma unroll
    for (int tt = 0; tt < 4; ++tt) vac[ct][tt] = (f4){0.f, 0.f, 0.f, 0.f};
#pragma unroll
  for (int ks = 0; ks < 4; ++ks) {
    s8 bfr[4];
#pragma unroll
    for (int tt = 0; tt < 4; ++tt)
      bfr[tt] = *(const s8*)&lds[(tt * 16 + r16) * 136 + ks * 32 + b4 * 8];
#pragma unroll
    for (int ct = 0; ct < 2; ++ct) {
      s8 af = *(const s8*)(wvb + (size_t)(h * 32 + ct * 16 + r16) * 128 + ks * 32 + b4 * 8);
#pragma unroll
      for (int tt = 0; tt < 4; ++tt)
        vac[ct][tt] = mfma16(af, bfr[tt], vac[ct][tt]);
    }
  }

  f4 sac[4][4];
#pragma unroll
  for (int a = 0; a < 4; ++a)
#pragma unroll
    for (int b = 0; b < 4; ++b) sac[a][b] = (f4){0.f, 0.f, 0.f, 0.f};
#pragma unroll
  for (int kt = 0; kt < 4; ++kt)
#pragma unroll
    for (int qt = 0; qt < 4; ++qt)
      sac[kt][qt] = mfma16(kf[kt], qf[qt], sac[kt][qt]);

  float scal = __expf(fminf(lsc[h], 4.60517019f));
  float rden[4];
#pragma unroll
  for (int qt = 0; qt < 4; ++qt) {
    float m = -1e30f;
#pragma unroll
    for (int kt = 0; kt < 4; ++kt) {
      f4 bv = *(const f4*)(bias + (h * 64 + qt * 16 + r16) * 64 + kt * 16 + b4 * 4);
#pragma unroll
      for (int r = 0; r < 4; ++r) {
        float sv = sac[kt][qt][r] * scal + bv[r];
        sac[kt][qt][r] = sv;
        m = fmaxf(m, sv);
      }
    }
    m = fmaxf(m, __shfl_xor(m, 16));
    m = fmaxf(m, __shfl_xor(m, 32));
    float sum = 0.f;
#pragma unroll
    for (int kt = 0; kt < 4; ++kt)
#pragma unroll
      for (int r = 0; r < 4; ++r) {
        float e = __expf(sac[kt][qt][r] - m);
        sac[kt][qt][r] = e;
        sum += e;
      }
    sum += __shfl_xor(sum, 16);
    sum += __shfl_xor(sum, 32);
    rden[qt] = 1.0f / sum;
  }

  __syncthreads();

  short* Vt = &lds[h * 6144];
  short* P  = &lds[h * 6144 + 2048];

#pragma unroll
  for (int ct = 0; ct < 2; ++ct)
#pragma unroll
    for (int r = 0; r < 4; ++r) {
      int row = ct * 16 + b4 * 4 + r;
      float bvl = vb[h * 32 + row];
#pragma unroll
      for (int tt = 0; tt < 4; ++tt) {
        int col = tt * 16 + r16;
        Vt[row * 64 + (col ^ SWZ(row))] = f2bf(vac[ct][tt][r] + bvl);
      }
    }
#pragma unroll
  for (int qt = 0; qt < 4; ++qt) {
    int q = qt * 16 + r16;
#pragma unroll
    for (int kt = 0; kt < 4; ++kt) {
      s4 p4;
#pragma unroll
      for (int r = 0; r < 4; ++r) p4[r] = f2bf(sac[kt][qt][r] * rden[qt]);
      *(s4*)&P[q * 64 + ((kt * 16 + b4 * 4) ^ SWZ(q))] = p4;
    }
  }

  f4 cac[2][4];
#pragma unroll
  for (int a = 0; a < 2; ++a)
#pragma unroll
    for (int b = 0; b < 4; ++b) cac[a][b] = (f4){0.f, 0.f, 0.f, 0.f};
#pragma unroll
  for (int ks = 0; ks < 2; ++ks) {
    s8 pf[4];
#pragma unroll
    for (int qt = 0; qt < 4; ++qt) {
      int q = qt * 16 + r16;
      pf[qt] = *(const s8*)&P[q * 64 + ((ks * 32 + b4 * 8) ^ SWZ(q))];
    }
#pragma unroll
    for (int dt = 0; dt < 2; ++dt) {
      int row = dt * 16 + r16;
      s8 vf = *(const s8*)&Vt[row * 64 + ((ks * 32 + b4 * 8) ^ SWZ(row))];
#pragma unroll
      for (int qt = 0; qt < 4; ++qt)
        cac[dt][qt] = mfma16(vf, pf[qt], cac[dt][qt]);
    }
  }
#pragma unroll
  for (int qt = 0; qt < 4; ++qt)
#pragma unroll
    for (int dt = 0; dt < 2; ++dt) {
      s4 o;
#pragma unroll
      for (int r = 0; r < 4; ++r) o[r] = f2bf(cac[dt][qt][r]);
      *(s4*)(ctx + (size_t)(bw * 64 + qt * 16 + r16) * 128 + h * 32 + dt * 16 + b4 * 4) = o;
    }
}

// ---------------------------------------------------------------- k_fuse
// R13 per-wave code, widened to 512 threads / 8 waves / M=128 rows per
// block (grid 1024): panel staging + barriers per row halve; 16 waves/CU.
__global__ __launch_bounds__(512, 4) void k_fuse(
    const short* __restrict__ ctx, const short* __restrict__ owb,
    const float* __restrict__ ob, const float* __restrict__ emb,
    const float* __restrict__ lnbw, const float* __restrict__ lnbb,
    const short* __restrict__ iwb, const float* __restrict__ ib,
    const short* __restrict__ fwb, const float* __restrict__ fb,
    const float* __restrict__ lnaw, const float* __restrict__ lnab,
    short* __restrict__ lo)
{
  __shared__ short Bs[128 * 136];      // 34816 B, shared weight panel
  __shared__ short ht[8][2184];        // 34944 B: hs tile, then f1 tile
  const int tid = threadIdx.x, lane = tid & 63, wv = tid >> 6;
  const int r16 = lane & 15, b4 = lane >> 4;
  const int obase = blockIdx.x * 128 + wv * 16;

  // ---- stage out_dense weights (2048 chunks / 512 threads = 4 iters)
#pragma unroll
  for (int it = 0; it < 4; ++it) {
    int ch = it * 512 + tid, n = ch >> 4, k8 = ch & 15;
    *(s8*)&Bs[n * 136 + k8 * 8] = *(const s8*)(owb + (size_t)n * 128 + k8 * 8);
  }
  __syncthreads();

  // ---- out-GEMM with inverse window-reverse gather
  int m = obase + r16;
  int bb = m >> 12, rimg = (m >> 6) & 63, cimg = m & 63;
  long tok = ((long)(bb * 64 + (rimg >> 3) * 8 + (cimg >> 3)) << 6)
           + (rimg & 7) * 8 + (cimg & 7);
  const short* ap = ctx + tok * 128;

  f4 acc[8];
#pragma unroll
  for (int nt = 0; nt < 8; ++nt) acc[nt] = (f4){0.f, 0.f, 0.f, 0.f};
#pragma unroll
  for (int ks = 0; ks < 4; ++ks) {
    s8 af = *(const s8*)(ap + ks * 32 + b4 * 8);
#pragma unroll
    for (int nt = 0; nt < 8; ++nt) {
      s8 bf = *(const s8*)&Bs[(nt * 16 + r16) * 136 + ks * 32 + b4 * 8];
      acc[nt] = mfma16(af, bf, acc[nt]);
    }
  }
  // LN_before + emb -> ht (for af1) AND lo (residual keep, global L2)
#pragma unroll
  for (int r = 0; r < 4; ++r) {
    int t = b4 * 4 + r;
    long orow = obase + t;
    float x[8];
    float s = 0.f, s2 = 0.f;
#pragma unroll
    for (int nt = 0; nt < 8; ++nt) {
      int c = nt * 16 + r16;
      x[nt] = acc[nt][r] + ob[c];
      s += x[nt]; s2 += x[nt] * x[nt];
    }
    s += __shfl_xor(s, 1); s += __shfl_xor(s, 2); s += __shfl_xor(s, 4); s += __shfl_xor(s, 8);
    s2 += __shfl_xor(s2, 1); s2 += __shfl_xor(s2, 2); s2 += __shfl_xor(s2, 4); s2 += __shfl_xor(s2, 8);
    float mu = s * (1.f / 128.f);
    float var = s2 * (1.f / 128.f) - mu * mu;
    float rs = rsqrtf(var + 1e-5f);
#pragma unroll
    for (int nt = 0; nt < 8; ++nt) {
      int c = nt * 16 + r16;
      float y = (x[nt] - mu) * rs * lnbw[c] + lnbb[c] + emb[orow * 128 + c];
      short yb = f2bf(y);
      ht[wv][t * 136 + c] = yb;
      lo[orow * 128 + c] = yb;
    }
  }

  // hs A-fragments (wave-private)
  s8 af1[4];
#pragma unroll
  for (int ks = 0; ks < 4; ++ks)
    af1[ks] = *(const s8*)&ht[wv][r16 * 136 + ks * 32 + b4 * 8];

  f4 acc2[8];
#pragma unroll
  for (int nt = 0; nt < 8; ++nt) acc2[nt] = (f4){0.f, 0.f, 0.f, 0.f};

  for (int cc = 0; cc < 4; ++cc) {
    int n0 = cc * 128;
    __syncthreads();
#pragma unroll
    for (int it = 0; it < 4; ++it) {
      int ch = it * 512 + tid, n = ch >> 4, k8 = ch & 15;
      *(s8*)&Bs[n * 136 + k8 * 8] = *(const s8*)(iwb + (size_t)(n0 + n) * 128 + k8 * 8);
    }
    __syncthreads();
    // ffn1 chunk
    f4 a1[8];
#pragma unroll
    for (int nt = 0; nt < 8; ++nt) a1[nt] = (f4){0.f, 0.f, 0.f, 0.f};
#pragma unroll
    for (int ks = 0; ks < 4; ++ks) {
#pragma unroll
      for (int nt = 0; nt < 8; ++nt) {
        s8 bf = *(const s8*)&Bs[(nt * 16 + r16) * 136 + ks * 32 + b4 * 8];
        a1[nt] = mfma16(af1[ks], bf, a1[nt]);
      }
    }
    // GELU (erff polynomial) -> ht (reused as f1 tile; wave-private)
#pragma unroll
    for (int r = 0; r < 4; ++r) {
      int t = b4 * 4 + r;
#pragma unroll
      for (int nt = 0; nt < 8; ++nt) {
        int c = nt * 16 + r16;
        float xg = a1[nt][r] + ib[n0 + c];
        float g = 0.5f * xg * (1.0f + erff(xg * 0.70710678118f));
        ht[wv][t * 136 + c] = f2bf(g);
      }
    }
    __syncthreads();
#pragma unroll
    for (int it = 0; it < 4; ++it) {
      int ch = it * 512 + tid, n = ch >> 4, k8 = ch & 15;
      *(s8*)&Bs[n * 136 + k8 * 8] = *(const s8*)(fwb + (size_t)n * 512 + n0 + k8 * 8);
    }
    __syncthreads();
    // ffn2 partial K
#pragma unroll
    for (int ks = 0; ks < 4; ++ks) {
      s8 af2 = *(const s8*)&ht[wv][r16 * 136 + ks * 32 + b4 * 8];
#pragma unroll
      for (int nt = 0; nt < 8; ++nt) {
        s8 bf = *(const s8*)&Bs[(nt * 16 + r16) * 136 + ks * 32 + b4 * 8];
        acc2[nt] = mfma16(af2, bf, acc2[nt]);
      }
    }
  }

  // ---- LN_after + residual (read back from lo, same-thread RAW) -> lo
#pragma unroll
  for (int r = 0; r < 4; ++r) {
    int t = b4 * 4 + r;
    long orow = obase + t;
    float x[8], res[8];
    float s = 0.f, s2 = 0.f;
#pragma unroll
    for (int nt = 0; nt < 8; ++nt) {
      int c = nt * 16 + r16;
      res[nt] = bf2f(lo[orow * 128 + c]);
      x[nt] = acc2[nt][r] + fb[c];
      s += x[nt]; s2 += x[nt] * x[nt];
    }
    s += __shfl_xor(s, 1); s += __shfl_xor(s, 2); s += __shfl_xor(s, 4); s += __shfl_xor(s, 8);
    s2 += __shfl_xor(s2, 1); s2 += __shfl_xor(s2, 2); s2 += __shfl_xor(s2, 4); s2 += __shfl_xor(s2, 8);
    float mu = s * (1.f / 128.f);
    float var = s2 * (1.f / 128.f) - mu * mu;
    float rs = rsqrtf(var + 1e-5f);
#pragma unroll
    for (int nt = 0; nt < 8; ++nt) {
      int c = nt * 16 + r16;
      float y = (x[nt] - mu) * rs * lnaw[c] + lnab[c] + res[nt];
      lo[orow * 128 + c] = f2bf(y);
    }
  }
}

// ---------------------------------------------------------------- k_merge
__global__ __launch_bounds__(256) void k_merge(
    const short* __restrict__ lo, const short* __restrict__ dwb,
    const float* __restrict__ dsw, const float* __restrict__ dsb,
    float* __restrict__ out)
{
  __shared__ short Bs[256 * 136];
  const int tid = threadIdx.x;
  const int lane = tid & 63, wv = tid >> 6, r16 = lane & 15, b4 = lane >> 4;
  const int mrow = blockIdx.x * 64 + wv * 16;
  f4 acc[16];
#pragma unroll
  for (int nt = 0; nt < 16; ++nt) acc[nt] = (f4){0.f, 0.f, 0.f, 0.f};
  for (int kc = 0; kc < 4; ++kc) {
    if (kc) __syncthreads();
#pragma unroll
    for (int it = 0; it < 16; ++it) {
      int ch = it * 256 + tid, n = ch >> 4, k8 = ch & 15;
      *(s8*)&Bs[n * 136 + k8 * 8] = *(const s8*)(dwb + (size_t)n * 512 + kc * 128 + k8 * 8);
    }
    __syncthreads();
    int m = mrow + r16;
    int bb = m >> 10, p = m & 1023, ii = p >> 5, jj = p & 31;
    long row = (long)bb * 4096 + (2 * ii + (kc & 1)) * 64 + (2 * jj + (kc >> 1));
    const short* ap = lo + row * 128;
#pragma unroll
    for (int ks = 0; ks < 4; ++ks) {
      s8 af = *(const s8*)(ap + ks * 32 + b4 * 8);
#pragma unroll
      for (int nt = 0; nt < 16; ++nt) {
        s8 bf = *(const s8*)&Bs[(nt * 16 + r16) * 136 + ks * 32 + b4 * 8];
        acc[nt] = mfma16(af, bf, acc[nt]);
      }
    }
  }
#pragma unroll
  for (int r = 0; r < 4; ++r) {
    size_t m = mrow + b4 * 4 + r;
    float x[16];
    float s = 0.f, s2 = 0.f;
#pragma unroll
    for (int nt = 0; nt < 16; ++nt) {
      x[nt] = acc[nt][r];
      s += x[nt]; s2 += x[nt] * x[nt];
    }
    s += __shfl_xor(s, 1); s += __shfl_xor(s, 2); s += __shfl_xor(s, 4); s += __shfl_xor(s, 8);
    s2 += __shfl_xor(s2, 1); s2 += __shfl_xor(s2, 2); s2 += __shfl_xor(s2, 4); s2 += __shfl_xor(s2, 8);
    float mu = s * (1.f / 256.f);
    float var = s2 * (1.f / 256.f) - mu * mu;
    float rs = rsqrtf(var + 1e-5f);
#pragma unroll
    for (int nt = 0; nt < 16; ++nt) {
      int c = nt * 16 + r16;
      out[m * 256 + c] = (x[nt] - mu) * rs * dsw[c] + dsb[c];
    }
  }
}

// ---------------------------------------------------------------- launch
extern "C" void kernel_launch(void* const* d_in, const int* in_sizes, int n_in,
                              void* d_out, int out_size, void* d_ws, size_t ws_size,
                              hipStream_t stream)
{
  const float* out_dense_b = (const float*)d_in[0];
  const float* out_dense_w = (const float*)d_in[1];
  const float* rel_tbl     = (const float*)d_in[2];
  const float* cpb0_b      = (const float*)d_in[3];
  const float* cpb0_w      = (const float*)d_in[4];
  const float* cpb2_w      = (const float*)d_in[5];
  const float* value_b     = (const float*)d_in[6];
  const float* value_w     = (const float*)d_in[7];
  const float* logit_scale = (const float*)d_in[8];
  const float* inter_b     = (const float*)d_in[9];
  const float* inter_w     = (const float*)d_in[10];
  const float* ln_after_b  = (const float*)d_in[11];
  const float* ln_after_w  = (const float*)d_in[12];
  const float* ln_before_b = (const float*)d_in[13];
  const float* ln_before_w = (const float*)d_in[14];
  const float* ffn_out_b   = (const float*)d_in[15];
  const float* ffn_out_w   = (const float*)d_in[16];
  const float* ds_norm_b   = (const float*)d_in[17];
  const float* ds_norm_w   = (const float*)d_in[18];
  const float* ds_red_w    = (const float*)d_in[19];
  const float* emb         = (const float*)d_in[20];
  const float* hsw         = (const float*)d_in[21];
  const float* keyl        = (const float*)d_in[22];
  const float* queryl      = (const float*)d_in[23];
  const int*   rpi         = (const int*)d_in[24];

  char* ws = (char*)d_ws;
  short* wsw  = (short*)ws;                                  // 589824 B
  float* bias = (float*)(ws + 589824);                       // 65536 B
  short* ctx  = (short*)(ws + 655360);                       // 33554432 B
  short* lo   = (short*)(ws + 655360 + 33554432ULL);         // 33554432 B

  short* wv_bf = wsw;
  short* ow_bf = wsw + 16384;
  short* iw_bf = wsw + 32768;
  short* fw_bf = wsw + 98304;
  short* dw_bf = wsw + 163840;

  k_prep<<<289, 256, 0, stream>>>(value_w, out_dense_w, inter_w, ffn_out_w, ds_red_w,
                                  rel_tbl, cpb0_b, cpb0_w, cpb2_w, rpi, wsw, bias);
  k_attn<<<2048, 256, 0, stream>>>(hsw, queryl, keyl, logit_scale, value_b, wv_bf, bias, ctx);
  k_fuse<<<1024, 512, 0, stream>>>(ctx, ow_bf, out_dense_b, emb, ln_before_w, ln_before_b,
                                   iw_bf, inter_b, fw_bf, ffn_out_b,
                                   ln_after_w, ln_after_b, lo);
  k_merge<<<512, 256, 0, stream>>>(lo, dw_bf, ds_norm_w, ds_norm_b, (float*)d_out);
}